// Round 2
// baseline (1325.200 us; speedup 1.0000x reference)
//
#include <hip/hip_runtime.h>
#include <hip/hip_bf16.h>

// GCN 2-layer forward:
//   hs1 = (z @ W1) * dinv ; acc1[d] += hs1[s] over edges
//   x1  = relu(dinv*(acc1 + hs1) + b1)
//   hs2 = (x1 @ W2) * dinv ; acc2[d] += hs2[s] over edges
//   out = dinv*(acc2 + hs2) + b2
// deg[i] = 1 + indeg(i) (self-loops folded into epilogue), dinv = rsqrt(deg).

#define WAVE 64

// ---------------- utility: zero-fill (avoids hipMemsetAsync entirely) -------
__global__ void zero_f32(float* __restrict__ p, size_t n) {
    size_t i = (size_t)blockIdx.x * blockDim.x + threadIdx.x;
    size_t stride = (size_t)gridDim.x * blockDim.x;
    for (; i < n; i += stride) p[i] = 0.0f;
}

// ---------------- degree ----------------
__global__ void deg_accum(const int* __restrict__ dst, float* __restrict__ deg, int E) {
    int i = blockIdx.x * blockDim.x + threadIdx.x;
    if (i < E) unsafeAtomicAdd(&deg[dst[i]], 1.0f);
}

__global__ void dinv_kernel(float* __restrict__ deg, int N) {
    int i = blockIdx.x * blockDim.x + threadIdx.x;
    if (i < N) deg[i] = rsqrtf(deg[i] + 1.0f);   // +1 = self-loop
}

// ---------------- GEMM with dinv-scaled epilogue ----------------
// out[r, c] = dinv[r] * sum_k A[r,k] * W[k,c]
// 256 threads, ROWS rows/block. c = tid % FOUT, rg = tid / FOUT,
// each thread computes RPT = ROWS/(256/FOUT) rows of one column.
// Wl reads broadcast across a wave's c-span partially; Al reads are
// wave-uniform per k (broadcast, conflict-free).
template<int K, int FOUT, int ROWS>
__global__ __launch_bounds__(256) void gemm_scaled(
        const float* __restrict__ A, const float* __restrict__ W,
        const float* __restrict__ dinv, float* __restrict__ out, int N)
{
    constexpr int G   = 256 / FOUT;   // row-groups per block
    constexpr int RPT = ROWS / G;     // rows per thread
    __shared__ float Wl[K * FOUT];
    __shared__ float Al[ROWS * K];

    const int tid  = threadIdx.x;
    const int row0 = blockIdx.x * ROWS;

    for (int i = tid; i < K * FOUT; i += 256) Wl[i] = W[i];
    for (int i = tid; i < ROWS * K; i += 256) {
        int r = i / K, k = i % K;
        int gr = row0 + r;
        Al[i] = (gr < N) ? A[(size_t)gr * K + k] : 0.0f;
    }
    __syncthreads();

    const int c  = tid % FOUT;
    const int rg = tid / FOUT;

    float acc[RPT];
#pragma unroll
    for (int r = 0; r < RPT; ++r) acc[r] = 0.0f;

#pragma unroll 4
    for (int k = 0; k < K; ++k) {
        float w = Wl[k * FOUT + c];
#pragma unroll
        for (int r = 0; r < RPT; ++r)
            acc[r] += Al[(rg * RPT + r) * K + k] * w;
    }

#pragma unroll
    for (int r = 0; r < RPT; ++r) {
        int gr = row0 + rg * RPT + r;
        if (gr < N) out[(size_t)gr * FOUT + c] = acc[r] * dinv[gr];
    }
}

// ---------------- edge scatter: acc[dst] += hs[src] ----------------
// One 64-lane wave per edge; lanes cover features (coalesced row gather,
// contiguous atomic burst).
template<int F>
__global__ __launch_bounds__(256) void edge_scatter(
        const float* __restrict__ hs, float* __restrict__ acc,
        const int* __restrict__ src, const int* __restrict__ dst, int E)
{
    int wid  = (int)((blockIdx.x * (size_t)blockDim.x + threadIdx.x) >> 6);
    int lane = threadIdx.x & 63;
    if (wid >= E) return;
    int s = src[wid];
    int d = dst[wid];
    const float* __restrict__ hrow = hs + (size_t)s * F;
    float* __restrict__ arow = acc + (size_t)d * F;
#pragma unroll
    for (int f = lane; f < F; f += WAVE)
        unsafeAtomicAdd(&arow[f], hrow[f]);
}

// ---------------- epilogue: out = [relu](dinv*(acc + hs) + b) ----------------
template<int F, bool RELU>
__global__ __launch_bounds__(256) void post_kernel(
        const float* __restrict__ acc, const float* __restrict__ hs,
        const float* __restrict__ dinv, const float* __restrict__ b,
        float* __restrict__ out, int N)
{
    constexpr int FV = F / 4;
    int i = blockIdx.x * blockDim.x + threadIdx.x;   // over N*F/4 float4s
    if (i >= N * FV) return;
    int node = i / FV;
    int fc   = i % FV;
    float di = dinv[node];
    float4 a  = ((const float4*)acc)[i];
    float4 h  = ((const float4*)hs)[i];
    float4 bb = ((const float4*)b)[fc];
    float4 o;
    o.x = di * (a.x + h.x) + bb.x;
    o.y = di * (a.y + h.y) + bb.y;
    o.z = di * (a.z + h.z) + bb.z;
    o.w = di * (a.w + h.w) + bb.w;
    if (RELU) {
        o.x = fmaxf(o.x, 0.0f); o.y = fmaxf(o.y, 0.0f);
        o.z = fmaxf(o.z, 0.0f); o.w = fmaxf(o.w, 0.0f);
    }
    ((float4*)out)[i] = o;
}

static inline size_t align_up(size_t x, size_t a) { return (x + a - 1) / a * a; }

extern "C" void kernel_launch(void* const* d_in, const int* in_sizes, int n_in,
                              void* d_out, int out_size, void* d_ws, size_t ws_size,
                              hipStream_t stream) {
    const float* z    = (const float*)d_in[0];   // [N,64]
    const int*   eidx = (const int*)d_in[1];     // [2,E] row-major: src then dst
    const float* W1   = (const float*)d_in[2];   // [64,128]
    const float* b1   = (const float*)d_in[3];   // [128]
    const float* W2   = (const float*)d_in[4];   // [128,64]
    const float* b2   = (const float*)d_in[5];   // [64]
    float* out = (float*)d_out;                  // [N,64]

    const int N = in_sizes[0] / 64;
    const int E = in_sizes[1] / 2;
    const int* src = eidx;
    const int* dst = eidx + E;

    constexpr int F1 = 128, F2 = 64, K1 = 64, K2 = 128;

    // Workspace layout (~103 MB): dinv | hs1 | acc1.
    // Layer-2 buffers reuse hs1's region (dead after post_kernel layer 1):
    //   hs2 = first half, acc2 = second half.
    char* ws = (char*)d_ws;
    size_t off = 0;
    float* dinv = (float*)(ws + off); off = align_up(off + (size_t)N * 4, 512);
    float* hs1  = (float*)(ws + off); off = align_up(off + (size_t)N * F1 * 4, 512);
    float* acc1 = (float*)(ws + off); off = align_up(off + (size_t)N * F1 * 4, 512);
    float* hs2  = hs1;
    float* acc2 = hs1 + (size_t)N * F2;
    (void)ws_size;

    const int ZB = 1024;   // blocks for grid-stride zero fill

    // ---- degrees ----
    zero_f32<<<ZB, 256, 0, stream>>>(dinv, (size_t)N);
    deg_accum<<<(E + 255) / 256, 256, 0, stream>>>(dst, dinv, E);
    dinv_kernel<<<(N + 255) / 256, 256, 0, stream>>>(dinv, N);

    // ---- layer 1 ----
    constexpr int ROWS = 32;
    gemm_scaled<K1, F1, ROWS><<<(N + ROWS - 1) / ROWS, 256, 0, stream>>>(z, W1, dinv, hs1, N);
    zero_f32<<<ZB, 256, 0, stream>>>(acc1, (size_t)N * F1);
    edge_scatter<F1><<<(E + 3) / 4, 256, 0, stream>>>(hs1, acc1, src, dst, E);
    // x1 = relu(dinv*(acc1+hs1)+b1), written in place into acc1
    post_kernel<F1, true><<<((size_t)N * F1 / 4 + 255) / 256, 256, 0, stream>>>(
        acc1, hs1, dinv, b1, acc1, N);

    // ---- layer 2 (hs1 region is now dead; reuse for hs2/acc2) ----
    gemm_scaled<K2, F2, ROWS><<<(N + ROWS - 1) / ROWS, 256, 0, stream>>>(acc1, W2, dinv, hs2, N);
    zero_f32<<<ZB, 256, 0, stream>>>(acc2, (size_t)N * F2);
    edge_scatter<F2><<<(E + 3) / 4, 256, 0, stream>>>(hs2, acc2, src, dst, E);
    post_kernel<F2, false><<<((size_t)N * F2 / 4 + 255) / 256, 256, 0, stream>>>(
        acc2, hs2, dinv, b2, out, N);
}

// Round 3
// 533.101 us; speedup vs baseline: 2.4858x; 2.4858x over previous
//
#include <hip/hip_runtime.h>
#include <hip/hip_bf16.h>

// GCN 2-layer forward, CSR-based (atomic-free aggregation):
//   deg[i] = 1 + indeg(i); dinv = rsqrt(deg)
//   CSR by dst built once per call (histogram -> scan -> scatter)
//   hs = (A @ W) * dinv          (gemm_scaled)
//   out[d] = [relu]( dinv[d]*(sum_{s->d} hs[s] + hs[d]) + b )   (aggregate)

#define WAVE 64

// ---------------- utility ----------------
__global__ void zero_i32(int* __restrict__ p, int n) {
    int i = blockIdx.x * blockDim.x + threadIdx.x;
    if (i < n) p[i] = 0;
}

// ---------------- degree ----------------
__global__ void deg_count(const int* __restrict__ dst, int* __restrict__ deg, int E) {
    int i = blockIdx.x * blockDim.x + threadIdx.x;
    if (i < E) atomicAdd(&deg[dst[i]], 1);
}

__global__ void dinv_from_deg(const int* __restrict__ deg, float* __restrict__ dinv, int N) {
    int i = blockIdx.x * blockDim.x + threadIdx.x;
    if (i < N) dinv[i] = rsqrtf((float)deg[i] + 1.0f);   // +1 = self-loop
}

// ---------------- prefix sum (exclusive) over deg -> rstart ----------------
// CHUNK = 1024 elements per block (256 threads x 4).
__global__ __launch_bounds__(256) void scan_block(
        const int* __restrict__ deg, int* __restrict__ rstart,
        int* __restrict__ bsum, int n)
{
    __shared__ int tmp[256];
    const int t  = threadIdx.x;
    const int i0 = blockIdx.x * 1024 + t * 4;
    int v[4], s = 0;
#pragma unroll
    for (int j = 0; j < 4; ++j) {
        int idx = i0 + j;
        v[j] = (idx < n) ? deg[idx] : 0;
        s += v[j];
    }
    tmp[t] = s;
    __syncthreads();
    for (int off = 1; off < 256; off <<= 1) {     // Hillis-Steele inclusive
        int x = (t >= off) ? tmp[t - off] : 0;
        __syncthreads();
        tmp[t] += x;
        __syncthreads();
    }
    int run = tmp[t] - s;                          // exclusive prefix in block
#pragma unroll
    for (int j = 0; j < 4; ++j) {
        int idx = i0 + j;
        if (idx < n) rstart[idx] = run;
        run += v[j];
    }
    if (t == 255) bsum[blockIdx.x] = tmp[255];     // block total
}

__global__ __launch_bounds__(256) void scan_sums(int* __restrict__ bsum, int B) {
    __shared__ int tmp[256];
    const int t = threadIdx.x;
    int v = (t < B) ? bsum[t] : 0;
    tmp[t] = v;
    __syncthreads();
    for (int off = 1; off < 256; off <<= 1) {
        int x = (t >= off) ? tmp[t - off] : 0;
        __syncthreads();
        tmp[t] += x;
        __syncthreads();
    }
    if (t < B) bsum[t] = tmp[t] - v;               // exclusive
}

__global__ void scan_add(int* __restrict__ rstart, const int* __restrict__ bsum, int n) {
    int i = blockIdx.x * blockDim.x + threadIdx.x;
    if (i < n) rstart[i] += bsum[i >> 10];
}

// ---------------- CSR scatter ----------------
// After this kernel rstart[n] = end-of-segment(n) (== original rstart[n+1]).
__global__ void csr_scatter(const int* __restrict__ src, const int* __restrict__ dst,
                            int* __restrict__ rstart, int* __restrict__ csr_src, int E)
{
    int i = blockIdx.x * blockDim.x + threadIdx.x;
    if (i < E) {
        int pos = atomicAdd(&rstart[dst[i]], 1);
        csr_src[pos] = src[i];
    }
}

// ---------------- GEMM with dinv-scaled epilogue ----------------
// out[r, :] = dinv[r] * (A[r, :] @ W)
// 256 threads; thread owns RPT rows x 4 consecutive cols (float4 W reads).
template<int K, int F, int ROWS>
__global__ __launch_bounds__(256) void gemm_scaled(
        const float* __restrict__ A, const float* __restrict__ W,
        const float* __restrict__ dinv, float* __restrict__ out, int N)
{
    constexpr int C4  = F / 4;        // float4 columns
    constexpr int G   = 256 / C4;     // row groups
    constexpr int RPT = ROWS / G;     // rows per thread
    __shared__ float4 Wl[K * C4];
    __shared__ float  Al[ROWS * K];

    const int tid  = threadIdx.x;
    const int row0 = blockIdx.x * ROWS;

    // stage W (vector copy)
    for (int i = tid; i < K * C4; i += 256) Wl[i] = ((const float4*)W)[i];
    // stage A tile (float4 per row-chunk)
    constexpr int KQ = K / 4;
    for (int i = tid; i < ROWS * KQ; i += 256) {
        int r = i / KQ, kq = i % KQ;
        int gr = row0 + r;
        float4 v = make_float4(0.f, 0.f, 0.f, 0.f);
        if (gr < N) v = ((const float4*)(A + (size_t)gr * K))[kq];
        ((float4*)&Al[r * K])[kq] = v;
    }
    __syncthreads();

    const int c4 = tid % C4;
    const int rg = tid / C4;

    float4 acc[RPT];
#pragma unroll
    for (int r = 0; r < RPT; ++r) acc[r] = make_float4(0.f, 0.f, 0.f, 0.f);

#pragma unroll 4
    for (int k = 0; k < K; ++k) {
        float4 w = Wl[k * C4 + c4];
#pragma unroll
        for (int r = 0; r < RPT; ++r) {
            float a = Al[(rg * RPT + r) * K + k];   // wave-broadcast
            acc[r].x += a * w.x;
            acc[r].y += a * w.y;
            acc[r].z += a * w.z;
            acc[r].w += a * w.w;
        }
    }

#pragma unroll
    for (int r = 0; r < RPT; ++r) {
        int gr = row0 + rg * RPT + r;
        if (gr < N) {
            float di = dinv[gr];
            float4 o = acc[r];
            o.x *= di; o.y *= di; o.z *= di; o.w *= di;
            ((float4*)(out + (size_t)gr * F))[c4] = o;
        }
    }
}

// ---------------- aggregation: out[d] = [relu](dinv*(sum hs[src] + hs[d]) + b) --
// One wave per node. Lanes cover features; 4-edge unroll for outstanding loads.
template<int F, bool RELU>
__global__ __launch_bounds__(256) void aggregate(
        const float* __restrict__ hs, const int* __restrict__ rend,
        const int* __restrict__ csr_src, const float* __restrict__ dinv,
        const float* __restrict__ b, float* __restrict__ out, int N)
{
    constexpr int PF = F / 64;   // floats per lane
    int node = (int)((blockIdx.x * (size_t)blockDim.x + threadIdx.x) >> 6);
    int lane = threadIdx.x & 63;
    if (node >= N) return;
    node = __builtin_amdgcn_readfirstlane(node);   // force SGPR: scalar loads below

    const int beg = node ? rend[node - 1] : 0;
    const int end = rend[node];

    float acc[PF];
#pragma unroll
    for (int p = 0; p < PF; ++p)
        acc[p] = hs[(size_t)node * F + p * 64 + lane];   // self-loop term

    int e = beg;
    for (; e + 4 <= end; e += 4) {
        int s0 = csr_src[e + 0], s1 = csr_src[e + 1];
        int s2 = csr_src[e + 2], s3 = csr_src[e + 3];
        const float* h0 = hs + (size_t)s0 * F;
        const float* h1 = hs + (size_t)s1 * F;
        const float* h2 = hs + (size_t)s2 * F;
        const float* h3 = hs + (size_t)s3 * F;
#pragma unroll
        for (int p = 0; p < PF; ++p) {
            int o = p * 64 + lane;
            float v0 = h0[o], v1 = h1[o], v2 = h2[o], v3 = h3[o];
            acc[p] += (v0 + v1) + (v2 + v3);
        }
    }
    for (; e < end; ++e) {
        const float* h = hs + (size_t)csr_src[e] * F;
#pragma unroll
        for (int p = 0; p < PF; ++p) acc[p] += h[p * 64 + lane];
    }

    const float di = dinv[node];
#pragma unroll
    for (int p = 0; p < PF; ++p) {
        float o = di * acc[p] + b[p * 64 + lane];
        if (RELU) o = fmaxf(o, 0.0f);
        out[(size_t)node * F + p * 64 + lane] = o;
    }
}

static inline size_t align_up(size_t x, size_t a) { return (x + a - 1) / a * a; }

extern "C" void kernel_launch(void* const* d_in, const int* in_sizes, int n_in,
                              void* d_out, int out_size, void* d_ws, size_t ws_size,
                              hipStream_t stream) {
    const float* z    = (const float*)d_in[0];   // [N,64]
    const int*   eidx = (const int*)d_in[1];     // [2,E]: src row then dst row
    const float* W1   = (const float*)d_in[2];   // [64,128]
    const float* b1   = (const float*)d_in[3];   // [128]
    const float* W2   = (const float*)d_in[4];   // [128,64]
    const float* b2   = (const float*)d_in[5];   // [64]
    float* out = (float*)d_out;                  // [N,64]

    const int N = in_sizes[0] / 64;
    const int E = in_sizes[1] / 2;
    const int* src = eidx;
    const int* dst = eidx + E;

    constexpr int F1 = 128, F2 = 64, K1 = 64, K2 = 128;

    // Workspace (~110 MB): dinv | deg | rstart | bsum | csr_src | hs1 | x1
    // hs2 aliases hs1 (dead once aggregate<128> has consumed it).
    char* ws = (char*)d_ws;
    size_t off = 0;
    float* dinv    = (float*)(ws + off); off = align_up(off + (size_t)N * 4, 512);
    int*   deg     = (int*)  (ws + off); off = align_up(off + (size_t)N * 4, 512);
    int*   rstart  = (int*)  (ws + off); off = align_up(off + (size_t)N * 4, 512);
    int*   bsum    = (int*)  (ws + off); off = align_up(off + 256 * 4, 512);
    int*   csr     = (int*)  (ws + off); off = align_up(off + (size_t)E * 4, 512);
    float* hs1     = (float*)(ws + off); off = align_up(off + (size_t)N * F1 * 4, 512);
    float* x1      = (float*)(ws + off); off = align_up(off + (size_t)N * F1 * 4, 512);
    float* hs2     = hs1;
    (void)ws_size;

    const int B = (N + 1023) / 1024;   // scan blocks (98 for N=100000, must be <=256)

    // ---- degrees + CSR build ----
    zero_i32<<<(N + 255) / 256, 256, 0, stream>>>(deg, N);
    deg_count<<<(E + 255) / 256, 256, 0, stream>>>(dst, deg, E);
    dinv_from_deg<<<(N + 255) / 256, 256, 0, stream>>>(deg, dinv, N);
    scan_block<<<B, 256, 0, stream>>>(deg, rstart, bsum, N);
    scan_sums<<<1, 256, 0, stream>>>(bsum, B);
    scan_add<<<(N + 255) / 256, 256, 0, stream>>>(rstart, bsum, N);
    csr_scatter<<<(E + 255) / 256, 256, 0, stream>>>(src, dst, rstart, csr, E);
    // rstart[n] is now end-of-segment(n)

    // ---- layer 1 ----
    constexpr int ROWS = 64;
    gemm_scaled<K1, F1, ROWS><<<(N + ROWS - 1) / ROWS, 256, 0, stream>>>(z, W1, dinv, hs1, N);
    aggregate<F1, true><<<(N + 3) / 4, 256, 0, stream>>>(hs1, rstart, csr, dinv, b1, x1, N);

    // ---- layer 2 ----
    gemm_scaled<K2, F2, ROWS><<<(N + ROWS - 1) / ROWS, 256, 0, stream>>>(x1, W2, dinv, hs2, N);
    aggregate<F2, false><<<(N + 3) / 4, 256, 0, stream>>>(hs2, rstart, csr, dinv, b2, out, N);
}

// Round 4
// 372.391 us; speedup vs baseline: 3.5586x; 1.4316x over previous
//
#include <hip/hip_runtime.h>
#include <hip/hip_bf16.h>

// GCN 2-layer forward, bucket-binned CSR (no global scans, LDS-local build):
//   bucket(node) = node >> 8   (256 nodes/bucket, fixed-capacity regions)
//   bin_edges : edges -> ebuf[bucket*CAP ...] (WG-batched global fetch-adds)
//   build_csr : per-bucket LDS histogram/prefix -> dinv, rbeg, rend, csr
//   hs = (A @ W) * dinv                        (gemm_scaled)
//   out[d] = [relu](dinv[d]*(sum hs[src] + hs[d]) + b)   (aggregate)

#define WAVE 64
#define BSHIFT 8
#define NPB 256              // nodes per bucket
#define CAP 5120             // max edges per bucket (mean 4096, +16 sigma)
#define CH 4096              // edges per WG in bin_edges
#define NBMAX 512

// ---------------- utility ----------------
__global__ void zero_i32(int* __restrict__ p, int n) {
    int i = blockIdx.x * blockDim.x + threadIdx.x;
    if (i < n) p[i] = 0;
}

// ---------------- bin_edges: scatter edges into bucket-strided ebuf ---------
// Two passes over this WG's chunk: LDS histogram -> one global fetch-add per
// touched bucket -> LDS-cursor ranked writes.
__global__ __launch_bounds__(256) void bin_edges(
        const int* __restrict__ src, const int* __restrict__ dst,
        int* __restrict__ bcursor, int2* __restrict__ ebuf, int E, int NB)
{
    __shared__ int hist[NBMAX];
    __shared__ int cur[NBMAX];
    const int t  = threadIdx.x;
    const int e0 = blockIdx.x * CH;

    for (int b = t; b < NB; b += 256) hist[b] = 0;
    __syncthreads();

#pragma unroll
    for (int j = 0; j < CH / 256; ++j) {
        int e = e0 + j * 256 + t;
        if (e < E) atomicAdd(&hist[dst[e] >> BSHIFT], 1);
    }
    __syncthreads();

    for (int b = t; b < NB; b += 256) {
        int c = hist[b];
        cur[b] = (c > 0) ? atomicAdd(&bcursor[b], c) : 0;   // bucket-local base
    }
    __syncthreads();

#pragma unroll
    for (int j = 0; j < CH / 256; ++j) {
        int e = e0 + j * 256 + t;
        if (e < E) {
            int s = src[e], d = dst[e];
            int b = d >> BSHIFT;
            int pos = atomicAdd(&cur[b], 1);                // LDS rank
            ebuf[(size_t)b * CAP + pos] = make_int2(s, d);
        }
    }
}

// ---------------- build_csr: one WG per bucket ----------------
// Produces dinv, rbeg, rend (absolute csr positions, bucket-strided), csr.
__global__ __launch_bounds__(256) void build_csr(
        const int2* __restrict__ ebuf, const int* __restrict__ bcursor,
        float* __restrict__ dinv, int* __restrict__ rbeg, int* __restrict__ rend,
        int* __restrict__ csr, int N)
{
    __shared__ int h[NPB];
    __shared__ int tmp[NPB];
    const int t   = threadIdx.x;
    const int b   = blockIdx.x;
    const int n0  = b << BSHIFT;
    const int cnt = bcursor[b];
    const size_t base = (size_t)b * CAP;

    h[t] = 0;
    __syncthreads();

    for (int i = t; i < cnt; i += 256)
        atomicAdd(&h[ebuf[base + i].y - n0], 1);
    __syncthreads();

    // exclusive prefix over 256 node degrees (Hillis-Steele)
    int deg = h[t];
    tmp[t] = deg;
    __syncthreads();
    for (int off = 1; off < 256; off <<= 1) {
        int x = (t >= off) ? tmp[t - off] : 0;
        __syncthreads();
        tmp[t] += x;
        __syncthreads();
    }
    int st = tmp[t] - deg;   // exclusive prefix within bucket

    int node = n0 + t;
    if (node < N) {
        dinv[node] = rsqrtf((float)deg + 1.0f);    // +1 = self-loop
        rbeg[node] = (int)base + st;
        rend[node] = (int)base + st + deg;
    }
    h[t] = st;               // becomes the scatter cursor
    __syncthreads();

    for (int i = t; i < cnt; i += 256) {
        int2 e = ebuf[base + i];
        int p = atomicAdd(&h[e.y - n0], 1);
        csr[base + p] = e.x;
    }
}

// ---------------- GEMM with dinv-scaled epilogue ----------------
// out[r, :] = dinv[r] * (A[r, :] @ W)
template<int K, int F, int ROWS>
__global__ __launch_bounds__(256) void gemm_scaled(
        const float* __restrict__ A, const float* __restrict__ W,
        const float* __restrict__ dinv, float* __restrict__ out, int N)
{
    constexpr int C4  = F / 4;
    constexpr int G   = 256 / C4;
    constexpr int RPT = ROWS / G;
    __shared__ float4 Wl[K * C4];
    __shared__ float  Al[ROWS * K];

    const int tid  = threadIdx.x;
    const int row0 = blockIdx.x * ROWS;

    for (int i = tid; i < K * C4; i += 256) Wl[i] = ((const float4*)W)[i];
    constexpr int KQ = K / 4;
    for (int i = tid; i < ROWS * KQ; i += 256) {
        int r = i / KQ, kq = i % KQ;
        int gr = row0 + r;
        float4 v = make_float4(0.f, 0.f, 0.f, 0.f);
        if (gr < N) v = ((const float4*)(A + (size_t)gr * K))[kq];
        ((float4*)&Al[r * K])[kq] = v;
    }
    __syncthreads();

    const int c4 = tid % C4;
    const int rg = tid / C4;

    float4 acc[RPT];
#pragma unroll
    for (int r = 0; r < RPT; ++r) acc[r] = make_float4(0.f, 0.f, 0.f, 0.f);

#pragma unroll 4
    for (int k = 0; k < K; ++k) {
        float4 w = Wl[k * C4 + c4];
#pragma unroll
        for (int r = 0; r < RPT; ++r) {
            float a = Al[(rg * RPT + r) * K + k];
            acc[r].x += a * w.x;
            acc[r].y += a * w.y;
            acc[r].z += a * w.z;
            acc[r].w += a * w.w;
        }
    }

#pragma unroll
    for (int r = 0; r < RPT; ++r) {
        int gr = row0 + rg * RPT + r;
        if (gr < N) {
            float di = dinv[gr];
            float4 o = acc[r];
            o.x *= di; o.y *= di; o.z *= di; o.w *= di;
            ((float4*)(out + (size_t)gr * F))[c4] = o;
        }
    }
}

// ---------------- aggregate F=128: float2/lane, one wave per node ----------
template<bool RELU>
__global__ __launch_bounds__(256) void aggregate128(
        const float* __restrict__ hs, const int* __restrict__ rbeg,
        const int* __restrict__ rend, const int* __restrict__ csr,
        const float* __restrict__ dinv, const float* __restrict__ b,
        float* __restrict__ out, int N)
{
    int node = (int)((blockIdx.x * (size_t)blockDim.x + threadIdx.x) >> 6);
    int lane = threadIdx.x & 63;
    if (node >= N) return;
    node = __builtin_amdgcn_readfirstlane(node);

    const int beg = rbeg[node];
    const int end = rend[node];
    const int o2  = lane * 2;

    float2 acc = *(const float2*)(hs + (size_t)node * 128 + o2);  // self-loop

    int e = beg;
    for (; e + 8 <= end; e += 8) {
        int s0 = csr[e+0], s1 = csr[e+1], s2 = csr[e+2], s3 = csr[e+3];
        int s4 = csr[e+4], s5 = csr[e+5], s6 = csr[e+6], s7 = csr[e+7];
        float2 v0 = *(const float2*)(hs + (size_t)s0 * 128 + o2);
        float2 v1 = *(const float2*)(hs + (size_t)s1 * 128 + o2);
        float2 v2 = *(const float2*)(hs + (size_t)s2 * 128 + o2);
        float2 v3 = *(const float2*)(hs + (size_t)s3 * 128 + o2);
        float2 v4 = *(const float2*)(hs + (size_t)s4 * 128 + o2);
        float2 v5 = *(const float2*)(hs + (size_t)s5 * 128 + o2);
        float2 v6 = *(const float2*)(hs + (size_t)s6 * 128 + o2);
        float2 v7 = *(const float2*)(hs + (size_t)s7 * 128 + o2);
        acc.x += ((v0.x + v1.x) + (v2.x + v3.x)) + ((v4.x + v5.x) + (v6.x + v7.x));
        acc.y += ((v0.y + v1.y) + (v2.y + v3.y)) + ((v4.y + v5.y) + (v6.y + v7.y));
    }
    for (; e < end; ++e) {
        float2 v = *(const float2*)(hs + (size_t)csr[e] * 128 + o2);
        acc.x += v.x; acc.y += v.y;
    }

    const float di = dinv[node];
    float2 bb = *(const float2*)(b + o2);
    float2 o;
    o.x = di * acc.x + bb.x;
    o.y = di * acc.y + bb.y;
    if (RELU) { o.x = fmaxf(o.x, 0.0f); o.y = fmaxf(o.y, 0.0f); }
    *(float2*)(out + (size_t)node * 128 + o2) = o;
}

// ---------------- aggregate F=64: float/lane, one wave per node ------------
template<bool RELU>
__global__ __launch_bounds__(256) void aggregate64(
        const float* __restrict__ hs, const int* __restrict__ rbeg,
        const int* __restrict__ rend, const int* __restrict__ csr,
        const float* __restrict__ dinv, const float* __restrict__ b,
        float* __restrict__ out, int N)
{
    int node = (int)((blockIdx.x * (size_t)blockDim.x + threadIdx.x) >> 6);
    int lane = threadIdx.x & 63;
    if (node >= N) return;
    node = __builtin_amdgcn_readfirstlane(node);

    const int beg = rbeg[node];
    const int end = rend[node];

    float acc = hs[(size_t)node * 64 + lane];   // self-loop

    int e = beg;
    for (; e + 8 <= end; e += 8) {
        int s0 = csr[e+0], s1 = csr[e+1], s2 = csr[e+2], s3 = csr[e+3];
        int s4 = csr[e+4], s5 = csr[e+5], s6 = csr[e+6], s7 = csr[e+7];
        float v0 = hs[(size_t)s0 * 64 + lane];
        float v1 = hs[(size_t)s1 * 64 + lane];
        float v2 = hs[(size_t)s2 * 64 + lane];
        float v3 = hs[(size_t)s3 * 64 + lane];
        float v4 = hs[(size_t)s4 * 64 + lane];
        float v5 = hs[(size_t)s5 * 64 + lane];
        float v6 = hs[(size_t)s6 * 64 + lane];
        float v7 = hs[(size_t)s7 * 64 + lane];
        acc += ((v0 + v1) + (v2 + v3)) + ((v4 + v5) + (v6 + v7));
    }
    for (; e < end; ++e)
        acc += hs[(size_t)csr[e] * 64 + lane];

    float o = dinv[node] * acc + b[lane];
    if (RELU) o = fmaxf(o, 0.0f);
    out[(size_t)node * 64 + lane] = o;
}

static inline size_t align_up(size_t x, size_t a) { return (x + a - 1) / a * a; }

extern "C" void kernel_launch(void* const* d_in, const int* in_sizes, int n_in,
                              void* d_out, int out_size, void* d_ws, size_t ws_size,
                              hipStream_t stream) {
    const float* z    = (const float*)d_in[0];   // [N,64]
    const int*   eidx = (const int*)d_in[1];     // [2,E]: src row then dst row
    const float* W1   = (const float*)d_in[2];   // [64,128]
    const float* b1   = (const float*)d_in[3];   // [128]
    const float* W2   = (const float*)d_in[4];   // [128,64]
    const float* b2   = (const float*)d_in[5];   // [64]
    float* out = (float*)d_out;                  // [N,64]

    const int N = in_sizes[0] / 64;
    const int E = in_sizes[1] / 2;
    const int* src = eidx;
    const int* dst = eidx + E;
    const int NB = (N + NPB - 1) >> BSHIFT;      // 391 for N=100000

    constexpr int F1 = 128, F2 = 64, K1 = 64, K2 = 128;

    // Workspace (~112 MB): dinv | rbeg | rend | bcursor | csr | hs1 | region2
    // region2 holds ebuf during CSR build, then x1 (ebuf dead after build_csr).
    char* ws = (char*)d_ws;
    size_t off = 0;
    float* dinv    = (float*)(ws + off); off = align_up(off + (size_t)N * 4, 512);
    int*   rbeg    = (int*)  (ws + off); off = align_up(off + (size_t)N * 4, 512);
    int*   rend    = (int*)  (ws + off); off = align_up(off + (size_t)N * 4, 512);
    int*   bcursor = (int*)  (ws + off); off = align_up(off + (size_t)NBMAX * 4, 512);
    int*   csr     = (int*)  (ws + off); off = align_up(off + (size_t)NB * CAP * 4, 512);
    float* hs1     = (float*)(ws + off); off = align_up(off + (size_t)N * F1 * 4, 512);
    char*  region2 = ws + off;           off = align_up(off + (size_t)N * F1 * 4, 512);
    int2*  ebuf    = (int2*)region2;     // NB*CAP*8 = 16 MB < N*F1*4 = 51 MB
    float* x1      = (float*)region2;
    float* hs2     = hs1;
    (void)ws_size;

    // ---- CSR build ----
    zero_i32<<<(NB + 255) / 256, 256, 0, stream>>>(bcursor, NB);
    bin_edges<<<(E + CH - 1) / CH, 256, 0, stream>>>(src, dst, bcursor, ebuf, E, NB);
    build_csr<<<NB, 256, 0, stream>>>(ebuf, bcursor, dinv, rbeg, rend, csr, N);

    // ---- layer 1 ----
    constexpr int ROWS = 64;
    gemm_scaled<K1, F1, ROWS><<<(N + ROWS - 1) / ROWS, 256, 0, stream>>>(z, W1, dinv, hs1, N);
    aggregate128<true><<<(N + 3) / 4, 256, 0, stream>>>(hs1, rbeg, rend, csr, dinv, b1, x1, N);

    // ---- layer 2 ----
    gemm_scaled<K2, F2, ROWS><<<(N + ROWS - 1) / ROWS, 256, 0, stream>>>(x1, W2, dinv, hs2, N);
    aggregate64<false><<<(N + 3) / 4, 256, 0, stream>>>(hs2, rbeg, rend, csr, dinv, b2, out, N);
}

// Round 5
// 318.720 us; speedup vs baseline: 4.1579x; 1.1684x over previous
//
#include <hip/hip_runtime.h>
#include <hip/hip_bf16.h>

// GCN 2-layer forward, bucket-binned CSR + pre-GEMM aggregation for layer 1:
//   u = z * dinv[:,None]                      [N,64]
//   agg1_d = u_d + sum_{s->d} u_s             (gather at 256 B/row)
//   x1 = relu(dinv_r*(agg1@W1) + b1)          (fused GEMM epilogue)
//   hs2 = dinv_r*(x1@W2)                      [N,64]
//   out_d = dinv_d*(hs2_d + sum hs2_s) + b2   (gather at 256 B/row)
// Aggregation commutes with the linear map, so layer 1 aggregates in the
// 64-dim input space instead of the 128-dim output space (halves gather).

#define WAVE 64
#define BSHIFT 8
#define NPB 256              // nodes per bucket
#define CAP 5120             // max edges per bucket (mean 4096, +16 sigma)
#define CH 4096              // edges per WG in bin_edges
#define NBMAX 512

// ---------------- utility ----------------
__global__ void zero_i32(int* __restrict__ p, int n) {
    int i = blockIdx.x * blockDim.x + threadIdx.x;
    if (i < n) p[i] = 0;
}

// ---------------- bin_edges: scatter edges into bucket-strided ebuf ---------
__global__ __launch_bounds__(256) void bin_edges(
        const int* __restrict__ src, const int* __restrict__ dst,
        int* __restrict__ bcursor, int2* __restrict__ ebuf, int E, int NB)
{
    __shared__ int hist[NBMAX];
    __shared__ int cur[NBMAX];
    const int t  = threadIdx.x;
    const int e0 = blockIdx.x * CH;

    for (int b = t; b < NB; b += 256) hist[b] = 0;
    __syncthreads();

#pragma unroll
    for (int j = 0; j < CH / 256; ++j) {
        int e = e0 + j * 256 + t;
        if (e < E) atomicAdd(&hist[dst[e] >> BSHIFT], 1);
    }
    __syncthreads();

    for (int b = t; b < NB; b += 256) {
        int c = hist[b];
        cur[b] = (c > 0) ? atomicAdd(&bcursor[b], c) : 0;
    }
    __syncthreads();

#pragma unroll
    for (int j = 0; j < CH / 256; ++j) {
        int e = e0 + j * 256 + t;
        if (e < E) {
            int s = src[e], d = dst[e];
            int b = d >> BSHIFT;
            int pos = atomicAdd(&cur[b], 1);
            ebuf[(size_t)b * CAP + pos] = make_int2(s, d);
        }
    }
}

// ---------------- build_csr: one WG per bucket ----------------
__global__ __launch_bounds__(256) void build_csr(
        const int2* __restrict__ ebuf, const int* __restrict__ bcursor,
        float* __restrict__ dinv, int* __restrict__ rbeg, int* __restrict__ rend,
        int* __restrict__ csr, int N)
{
    __shared__ int h[NPB];
    __shared__ int tmp[NPB];
    const int t   = threadIdx.x;
    const int b   = blockIdx.x;
    const int n0  = b << BSHIFT;
    const int cnt = bcursor[b];
    const size_t base = (size_t)b * CAP;

    h[t] = 0;
    __syncthreads();

    for (int i = t; i < cnt; i += 256)
        atomicAdd(&h[ebuf[base + i].y - n0], 1);
    __syncthreads();

    int deg = h[t];
    tmp[t] = deg;
    __syncthreads();
    for (int off = 1; off < 256; off <<= 1) {
        int x = (t >= off) ? tmp[t - off] : 0;
        __syncthreads();
        tmp[t] += x;
        __syncthreads();
    }
    int st = tmp[t] - deg;

    int node = n0 + t;
    if (node < N) {
        dinv[node] = rsqrtf((float)deg + 1.0f);
        rbeg[node] = (int)base + st;
        rend[node] = (int)base + st + deg;
    }
    h[t] = st;
    __syncthreads();

    for (int i = t; i < cnt; i += 256) {
        int2 e = ebuf[base + i];
        int p = atomicAdd(&h[e.y - n0], 1);
        csr[base + p] = e.x;
    }
}

// ---------------- scale: u = z * dinv[:,None]  (float4 over [N,16]) --------
__global__ void scale_rows64(const float* __restrict__ z, const float* __restrict__ dinv,
                             float* __restrict__ u, int N)
{
    int i = blockIdx.x * blockDim.x + threadIdx.x;
    if (i >= N * 16) return;
    float di = dinv[i >> 4];
    float4 v = ((const float4*)z)[i];
    v.x *= di; v.y *= di; v.z *= di; v.w *= di;
    ((float4*)u)[i] = v;
}

// ---------------- GEMM, dinv-scaled epilogue (+optional bias/relu) ----------
// out[r, :] = [relu]( dinv[r] * (A[r, :] @ W) [+ b] )
template<int K, int F, int ROWS, bool ADD_BIAS, bool RELU>
__global__ __launch_bounds__(256) void gemm_fused(
        const float* __restrict__ A, const float* __restrict__ W,
        const float* __restrict__ dinv, const float* __restrict__ b,
        float* __restrict__ out, int N)
{
    constexpr int C4  = F / 4;
    constexpr int G   = 256 / C4;
    constexpr int RPT = ROWS / G;
    __shared__ float4 Wl[K * C4];
    __shared__ float  Al[ROWS * K];

    const int tid  = threadIdx.x;
    const int row0 = blockIdx.x * ROWS;

    for (int i = tid; i < K * C4; i += 256) Wl[i] = ((const float4*)W)[i];
    constexpr int KQ = K / 4;
    for (int i = tid; i < ROWS * KQ; i += 256) {
        int r = i / KQ, kq = i % KQ;
        int gr = row0 + r;
        float4 v = make_float4(0.f, 0.f, 0.f, 0.f);
        if (gr < N) v = ((const float4*)(A + (size_t)gr * K))[kq];
        ((float4*)&Al[r * K])[kq] = v;
    }
    __syncthreads();

    const int c4 = tid % C4;
    const int rg = tid / C4;

    float4 acc[RPT];
#pragma unroll
    for (int r = 0; r < RPT; ++r) acc[r] = make_float4(0.f, 0.f, 0.f, 0.f);

#pragma unroll 4
    for (int k = 0; k < K; ++k) {
        float4 w = Wl[k * C4 + c4];
#pragma unroll
        for (int r = 0; r < RPT; ++r) {
            float a = Al[(rg * RPT + r) * K + k];
            acc[r].x += a * w.x;
            acc[r].y += a * w.y;
            acc[r].z += a * w.z;
            acc[r].w += a * w.w;
        }
    }

#pragma unroll
    for (int r = 0; r < RPT; ++r) {
        int gr = row0 + rg * RPT + r;
        if (gr < N) {
            float di = dinv[gr];
            float4 o = acc[r];
            o.x *= di; o.y *= di; o.z *= di; o.w *= di;
            if (ADD_BIAS) {
                float4 bb = ((const float4*)b)[c4];
                o.x += bb.x; o.y += bb.y; o.z += bb.z; o.w += bb.w;
            }
            if (RELU) {
                o.x = fmaxf(o.x, 0.0f); o.y = fmaxf(o.y, 0.0f);
                o.z = fmaxf(o.z, 0.0f); o.w = fmaxf(o.w, 0.0f);
            }
            ((float4*)(out + (size_t)gr * F))[c4] = o;
        }
    }
}

// ---------------- aggregate (F=64), one wave per node, 16-edge unroll ------
// PRE:  out_d = hs_d + sum hs_s                (POST=false)
// POST: out_d = dinv_d*(hs_d + sum hs_s) + b   (POST=true)
template<bool POST>
__global__ __launch_bounds__(256) void aggregate64(
        const float* __restrict__ hs, const int* __restrict__ rbeg,
        const int* __restrict__ rend, const int* __restrict__ csr,
        const float* __restrict__ dinv, const float* __restrict__ b,
        float* __restrict__ out, int N)
{
    int node = (int)((blockIdx.x * (size_t)blockDim.x + threadIdx.x) >> 6);
    int lane = threadIdx.x & 63;
    if (node >= N) return;
    node = __builtin_amdgcn_readfirstlane(node);   // wave-uniform -> scalar loads

    const int beg = rbeg[node];
    const int end = rend[node];

    float acc = hs[(size_t)node * 64 + lane];      // self-loop term

    int e = beg;
    for (; e + 16 <= end; e += 16) {
        int s[16];
#pragma unroll
        for (int j = 0; j < 16; ++j) s[j] = csr[e + j];
        float v[16];
#pragma unroll
        for (int j = 0; j < 16; ++j) v[j] = hs[(size_t)s[j] * 64 + lane];
        float t0 = ((v[0] + v[1]) + (v[2] + v[3])) + ((v[4] + v[5]) + (v[6] + v[7]));
        float t1 = ((v[8] + v[9]) + (v[10] + v[11])) + ((v[12] + v[13]) + (v[14] + v[15]));
        acc += t0 + t1;
    }
    for (; e + 4 <= end; e += 4) {
        int s0 = csr[e+0], s1 = csr[e+1], s2 = csr[e+2], s3 = csr[e+3];
        float v0 = hs[(size_t)s0 * 64 + lane];
        float v1 = hs[(size_t)s1 * 64 + lane];
        float v2 = hs[(size_t)s2 * 64 + lane];
        float v3 = hs[(size_t)s3 * 64 + lane];
        acc += (v0 + v1) + (v2 + v3);
    }
    for (; e < end; ++e)
        acc += hs[(size_t)csr[e] * 64 + lane];

    float o = acc;
    if (POST) o = dinv[node] * acc + b[lane];
    out[(size_t)node * 64 + lane] = o;
}

static inline size_t align_up(size_t x, size_t a) { return (x + a - 1) / a * a; }

extern "C" void kernel_launch(void* const* d_in, const int* in_sizes, int n_in,
                              void* d_out, int out_size, void* d_ws, size_t ws_size,
                              hipStream_t stream) {
    const float* z    = (const float*)d_in[0];   // [N,64]
    const int*   eidx = (const int*)d_in[1];     // [2,E]: src row then dst row
    const float* W1   = (const float*)d_in[2];   // [64,128]
    const float* b1   = (const float*)d_in[3];   // [128]
    const float* W2   = (const float*)d_in[4];   // [128,64]
    const float* b2   = (const float*)d_in[5];   // [64]
    float* out = (float*)d_out;                  // [N,64]

    const int N = in_sizes[0] / 64;
    const int E = in_sizes[1] / 2;
    const int* src = eidx;
    const int* dst = eidx + E;
    const int NB = (N + NPB - 1) >> BSHIFT;      // 391 for N=100000

    // Workspace (~103 MB): small arrays | bufA [N,64] | bufB [N,64] | bufC [N,128]
    // ebuf (16 MB) aliases bufC; x1 overwrites it after build_csr is done.
    char* ws = (char*)d_ws;
    size_t off = 0;
    float* dinv    = (float*)(ws + off); off = align_up(off + (size_t)N * 4, 512);
    int*   rbeg    = (int*)  (ws + off); off = align_up(off + (size_t)N * 4, 512);
    int*   rend    = (int*)  (ws + off); off = align_up(off + (size_t)N * 4, 512);
    int*   bcursor = (int*)  (ws + off); off = align_up(off + (size_t)NBMAX * 4, 512);
    int*   csr     = (int*)  (ws + off); off = align_up(off + (size_t)NB * CAP * 4, 512);
    float* bufA    = (float*)(ws + off); off = align_up(off + (size_t)N * 64 * 4, 512);
    float* bufB    = (float*)(ws + off); off = align_up(off + (size_t)N * 64 * 4, 512);
    float* bufC    = (float*)(ws + off); off = align_up(off + (size_t)N * 128 * 4, 512);
    int2*  ebuf    = (int2*)bufC;
    (void)ws_size;

    float* u    = bufA;   // z * dinv
    float* agg1 = bufB;   // aggregated u
    float* x1   = bufC;   // layer-1 output
    float* hs2  = bufA;   // layer-2 pre-aggregate (u is dead by then)

    // ---- CSR build ----
    zero_i32<<<(NB + 255) / 256, 256, 0, stream>>>(bcursor, NB);
    bin_edges<<<(E + CH - 1) / CH, 256, 0, stream>>>(src, dst, bcursor, ebuf, E, NB);
    build_csr<<<NB, 256, 0, stream>>>(ebuf, bcursor, dinv, rbeg, rend, csr, N);

    // ---- layer 1 (aggregate pre-GEMM in 64-dim space) ----
    scale_rows64<<<((size_t)N * 16 + 255) / 256, 256, 0, stream>>>(z, dinv, u, N);
    aggregate64<false><<<(N + 3) / 4, 256, 0, stream>>>(u, rbeg, rend, csr, dinv, nullptr, agg1, N);
    constexpr int ROWS = 64;
    gemm_fused<64, 128, ROWS, true, true><<<(N + ROWS - 1) / ROWS, 256, 0, stream>>>(
        agg1, W1, dinv, b1, x1, N);

    // ---- layer 2 (aggregate post-GEMM in 64-dim space) ----
    gemm_fused<128, 64, ROWS, false, false><<<(N + ROWS - 1) / ROWS, 256, 0, stream>>>(
        x1, W2, dinv, nullptr, hs2, N);
    aggregate64<true><<<(N + 3) / 4, 256, 0, stream>>>(hs2, rbeg, rend, csr, dinv, b2, out, N);
}

// Round 6
// 311.612 us; speedup vs baseline: 4.2527x; 1.0228x over previous
//
#include <hip/hip_runtime.h>
#include <hip/hip_bf16.h>

// GCN 2-layer forward, bucket-binned CSR + pre-GEMM aggregation for layer 1:
//   u = z * dinv[:,None]                      [N,64]
//   agg1_d = u_d + sum_{s->d} u_s             (gather at 256 B/row)
//   x1 = relu(dinv_r*(agg1@W1) + b1)          (fused GEMM epilogue)
//   hs2 = dinv_r*(x1@W2)                      [N,64]
//   out_d = dinv_d*(hs2_d + sum hs2_s) + b2   (gather at 256 B/row)
// Aggregation commutes with the linear map -> layer 1 aggregates in the
// 64-dim input space (halves gather vs 128-dim).
// GEMM inner loop is k-blocked by 4 with float4 LDS reads on both operands
// so LDS issue (~144 cyc/kq) hides under FMA work (~256 cyc/kq).

#define WAVE 64
#define BSHIFT 8
#define NPB 256              // nodes per bucket
#define CAP 5120             // max edges per bucket (mean 4096, +16 sigma)
#define CH 4096              // edges per WG in bin_edges
#define NBMAX 512

// ---------------- utility ----------------
__global__ void zero_i32(int* __restrict__ p, int n) {
    int i = blockIdx.x * blockDim.x + threadIdx.x;
    if (i < n) p[i] = 0;
}

// ---------------- bin_edges: scatter edges into bucket-strided ebuf ---------
__global__ __launch_bounds__(256) void bin_edges(
        const int* __restrict__ src, const int* __restrict__ dst,
        int* __restrict__ bcursor, int2* __restrict__ ebuf, int E, int NB)
{
    __shared__ int hist[NBMAX];
    __shared__ int cur[NBMAX];
    const int t  = threadIdx.x;
    const int e0 = blockIdx.x * CH;

    for (int b = t; b < NB; b += 256) hist[b] = 0;
    __syncthreads();

#pragma unroll
    for (int j = 0; j < CH / 256; ++j) {
        int e = e0 + j * 256 + t;
        if (e < E) atomicAdd(&hist[dst[e] >> BSHIFT], 1);
    }
    __syncthreads();

    for (int b = t; b < NB; b += 256) {
        int c = hist[b];
        cur[b] = (c > 0) ? atomicAdd(&bcursor[b], c) : 0;
    }
    __syncthreads();

#pragma unroll
    for (int j = 0; j < CH / 256; ++j) {
        int e = e0 + j * 256 + t;
        if (e < E) {
            int s = src[e], d = dst[e];
            int b = d >> BSHIFT;
            int pos = atomicAdd(&cur[b], 1);
            ebuf[(size_t)b * CAP + pos] = make_int2(s, d);
        }
    }
}

// ---------------- build_csr: one WG per bucket ----------------
__global__ __launch_bounds__(256) void build_csr(
        const int2* __restrict__ ebuf, const int* __restrict__ bcursor,
        float* __restrict__ dinv, int* __restrict__ rbeg, int* __restrict__ rend,
        int* __restrict__ csr, int N)
{
    __shared__ int h[NPB];
    __shared__ int tmp[NPB];
    const int t   = threadIdx.x;
    const int b   = blockIdx.x;
    const int n0  = b << BSHIFT;
    const int cnt = bcursor[b];
    const size_t base = (size_t)b * CAP;

    h[t] = 0;
    __syncthreads();

    for (int i = t; i < cnt; i += 256)
        atomicAdd(&h[ebuf[base + i].y - n0], 1);
    __syncthreads();

    int deg = h[t];
    tmp[t] = deg;
    __syncthreads();
    for (int off = 1; off < 256; off <<= 1) {
        int x = (t >= off) ? tmp[t - off] : 0;
        __syncthreads();
        tmp[t] += x;
        __syncthreads();
    }
    int st = tmp[t] - deg;

    int node = n0 + t;
    if (node < N) {
        dinv[node] = rsqrtf((float)deg + 1.0f);
        rbeg[node] = (int)base + st;
        rend[node] = (int)base + st + deg;
    }
    h[t] = st;
    __syncthreads();

    for (int i = t; i < cnt; i += 256) {
        int2 e = ebuf[base + i];
        int p = atomicAdd(&h[e.y - n0], 1);
        csr[base + p] = e.x;
    }
}

// ---------------- scale: u = z * dinv[:,None]  (float4 over [N,16]) --------
__global__ void scale_rows64(const float* __restrict__ z, const float* __restrict__ dinv,
                             float* __restrict__ u, int N)
{
    int i = blockIdx.x * blockDim.x + threadIdx.x;
    if (i >= N * 16) return;
    float di = dinv[i >> 4];
    float4 v = ((const float4*)z)[i];
    v.x *= di; v.y *= di; v.z *= di; v.w *= di;
    ((float4*)u)[i] = v;
}

// ---------------- GEMM, dinv-scaled epilogue (+optional bias/relu) ----------
// out[r, :] = [relu]( dinv[r] * (A[r, :] @ W) [+ b] )
// k-blocked by 4: A staged as float4 (over k), W read as 4 float4 rows.
template<int K, int F, int ROWS, bool ADD_BIAS, bool RELU>
__global__ __launch_bounds__(256) void gemm_fused(
        const float* __restrict__ A, const float* __restrict__ W,
        const float* __restrict__ dinv, const float* __restrict__ b,
        float* __restrict__ out, int N)
{
    constexpr int C4  = F / 4;        // float4 output columns
    constexpr int G   = 256 / C4;     // row groups
    constexpr int RPT = ROWS / G;     // rows per thread
    constexpr int KQ  = K / 4;        // float4 k-chunks
    constexpr int AST = KQ + 1;       // padded A row stride (breaks bank alias)
    __shared__ float4 Wl[K * C4];     // 32 KB both layers
    __shared__ float4 Al[ROWS * AST];

    const int tid  = threadIdx.x;
    const int row0 = blockIdx.x * ROWS;

    for (int i = tid; i < K * C4; i += 256) Wl[i] = ((const float4*)W)[i];
    for (int i = tid; i < ROWS * KQ; i += 256) {
        int r = i / KQ, kq = i % KQ;
        int gr = row0 + r;
        float4 v = make_float4(0.f, 0.f, 0.f, 0.f);
        if (gr < N) v = ((const float4*)(A + (size_t)gr * K))[kq];
        Al[r * AST + kq] = v;
    }
    __syncthreads();

    const int c4 = tid % C4;
    const int rg = tid / C4;

    float4 acc[RPT];
#pragma unroll
    for (int r = 0; r < RPT; ++r) acc[r] = make_float4(0.f, 0.f, 0.f, 0.f);

#pragma unroll 2
    for (int kq = 0; kq < KQ; ++kq) {
        float4 w0 = Wl[(4 * kq + 0) * C4 + c4];
        float4 w1 = Wl[(4 * kq + 1) * C4 + c4];
        float4 w2 = Wl[(4 * kq + 2) * C4 + c4];
        float4 w3 = Wl[(4 * kq + 3) * C4 + c4];
#pragma unroll
        for (int r = 0; r < RPT; ++r) {
            float4 a = Al[(rg * RPT + r) * AST + kq];
            acc[r].x += a.x * w0.x; acc[r].y += a.x * w0.y;
            acc[r].z += a.x * w0.z; acc[r].w += a.x * w0.w;
            acc[r].x += a.y * w1.x; acc[r].y += a.y * w1.y;
            acc[r].z += a.y * w1.z; acc[r].w += a.y * w1.w;
            acc[r].x += a.z * w2.x; acc[r].y += a.z * w2.y;
            acc[r].z += a.z * w2.z; acc[r].w += a.z * w2.w;
            acc[r].x += a.w * w3.x; acc[r].y += a.w * w3.y;
            acc[r].z += a.w * w3.z; acc[r].w += a.w * w3.w;
        }
    }

#pragma unroll
    for (int r = 0; r < RPT; ++r) {
        int gr = row0 + rg * RPT + r;
        if (gr < N) {
            float di = dinv[gr];
            float4 o = acc[r];
            o.x *= di; o.y *= di; o.z *= di; o.w *= di;
            if (ADD_BIAS) {
                float4 bb = ((const float4*)b)[c4];
                o.x += bb.x; o.y += bb.y; o.z += bb.z; o.w += bb.w;
            }
            if (RELU) {
                o.x = fmaxf(o.x, 0.0f); o.y = fmaxf(o.y, 0.0f);
                o.z = fmaxf(o.z, 0.0f); o.w = fmaxf(o.w, 0.0f);
            }
            ((float4*)(out + (size_t)gr * F))[c4] = o;
        }
    }
}

// ---------------- aggregate (F=64), one wave per node, 16-edge unroll ------
// PRE:  out_d = hs_d + sum hs_s                (POST=false)
// POST: out_d = dinv_d*(hs_d + sum hs_s) + b   (POST=true)
template<bool POST>
__global__ __launch_bounds__(256) void aggregate64(
        const float* __restrict__ hs, const int* __restrict__ rbeg,
        const int* __restrict__ rend, const int* __restrict__ csr,
        const float* __restrict__ dinv, const float* __restrict__ b,
        float* __restrict__ out, int N)
{
    int node = (int)((blockIdx.x * (size_t)blockDim.x + threadIdx.x) >> 6);
    int lane = threadIdx.x & 63;
    if (node >= N) return;
    node = __builtin_amdgcn_readfirstlane(node);   // wave-uniform -> scalar loads

    const int beg = rbeg[node];
    const int end = rend[node];

    float acc = hs[(size_t)node * 64 + lane];      // self-loop term

    int e = beg;
    for (; e + 16 <= end; e += 16) {
        int s[16];
#pragma unroll
        for (int j = 0; j < 16; ++j) s[j] = csr[e + j];
        float v[16];
#pragma unroll
        for (int j = 0; j < 16; ++j) v[j] = hs[(size_t)s[j] * 64 + lane];
        float t0 = ((v[0] + v[1]) + (v[2] + v[3])) + ((v[4] + v[5]) + (v[6] + v[7]));
        float t1 = ((v[8] + v[9]) + (v[10] + v[11])) + ((v[12] + v[13]) + (v[14] + v[15]));
        acc += t0 + t1;
    }
    for (; e + 4 <= end; e += 4) {
        int s0 = csr[e+0], s1 = csr[e+1], s2 = csr[e+2], s3 = csr[e+3];
        float v0 = hs[(size_t)s0 * 64 + lane];
        float v1 = hs[(size_t)s1 * 64 + lane];
        float v2 = hs[(size_t)s2 * 64 + lane];
        float v3 = hs[(size_t)s3 * 64 + lane];
        acc += (v0 + v1) + (v2 + v3);
    }
    for (; e < end; ++e)
        acc += hs[(size_t)csr[e] * 64 + lane];

    float o = acc;
    if (POST) o = dinv[node] * acc + b[lane];
    out[(size_t)node * 64 + lane] = o;
}

static inline size_t align_up(size_t x, size_t a) { return (x + a - 1) / a * a; }

extern "C" void kernel_launch(void* const* d_in, const int* in_sizes, int n_in,
                              void* d_out, int out_size, void* d_ws, size_t ws_size,
                              hipStream_t stream) {
    const float* z    = (const float*)d_in[0];   // [N,64]
    const int*   eidx = (const int*)d_in[1];     // [2,E]: src row then dst row
    const float* W1   = (const float*)d_in[2];   // [64,128]
    const float* b1   = (const float*)d_in[3];   // [128]
    const float* W2   = (const float*)d_in[4];   // [128,64]
    const float* b2   = (const float*)d_in[5];   // [64]
    float* out = (float*)d_out;                  // [N,64]

    const int N = in_sizes[0] / 64;
    const int E = in_sizes[1] / 2;
    const int* src = eidx;
    const int* dst = eidx + E;
    const int NB = (N + NPB - 1) >> BSHIFT;      // 391 for N=100000

    // Workspace (~103 MB): small arrays | bufA [N,64] | bufB [N,64] | bufC [N,128]
    // ebuf (16 MB) aliases bufC; x1 overwrites it after build_csr is done.
    char* ws = (char*)d_ws;
    size_t off = 0;
    float* dinv    = (float*)(ws + off); off = align_up(off + (size_t)N * 4, 512);
    int*   rbeg    = (int*)  (ws + off); off = align_up(off + (size_t)N * 4, 512);
    int*   rend    = (int*)  (ws + off); off = align_up(off + (size_t)N * 4, 512);
    int*   bcursor = (int*)  (ws + off); off = align_up(off + (size_t)NBMAX * 4, 512);
    int*   csr     = (int*)  (ws + off); off = align_up(off + (size_t)NB * CAP * 4, 512);
    float* bufA    = (float*)(ws + off); off = align_up(off + (size_t)N * 64 * 4, 512);
    float* bufB    = (float*)(ws + off); off = align_up(off + (size_t)N * 64 * 4, 512);
    float* bufC    = (float*)(ws + off); off = align_up(off + (size_t)N * 128 * 4, 512);
    int2*  ebuf    = (int2*)bufC;
    (void)ws_size;

    float* u    = bufA;   // z * dinv
    float* agg1 = bufB;   // aggregated u
    float* x1   = bufC;   // layer-1 output
    float* hs2  = bufA;   // layer-2 pre-aggregate (u is dead by then)

    // ---- CSR build ----
    zero_i32<<<(NB + 255) / 256, 256, 0, stream>>>(bcursor, NB);
    bin_edges<<<(E + CH - 1) / CH, 256, 0, stream>>>(src, dst, bcursor, ebuf, E, NB);
    build_csr<<<NB, 256, 0, stream>>>(ebuf, bcursor, dinv, rbeg, rend, csr, N);

    // ---- layer 1 (aggregate pre-GEMM in 64-dim space) ----
    scale_rows64<<<((size_t)N * 16 + 255) / 256, 256, 0, stream>>>(z, dinv, u, N);
    aggregate64<false><<<(N + 3) / 4, 256, 0, stream>>>(u, rbeg, rend, csr, dinv, nullptr, agg1, N);
    constexpr int ROWS = 64;
    gemm_fused<64, 128, ROWS, true, true><<<(N + ROWS - 1) / ROWS, 256, 0, stream>>>(
        agg1, W1, dinv, b1, x1, N);

    // ---- layer 2 (aggregate post-GEMM in 64-dim space) ----
    gemm_fused<128, 64, ROWS, false, false><<<(N + ROWS - 1) / ROWS, 256, 0, stream>>>(
        x1, W2, dinv, nullptr, hs2, N);
    aggregate64<true><<<(N + 3) / 4, 256, 0, stream>>>(hs2, rbeg, rend, csr, dinv, b2, out, N);
}

// Round 7
// 280.854 us; speedup vs baseline: 4.7185x; 1.1095x over previous
//
#include <hip/hip_runtime.h>
#include <hip/hip_bf16.h>

// GCN 2-layer forward, bucket-binned CSR + pre-GEMM aggregation (layer 1)
// + bf16 gather operands (halves the compulsory per-XCD gather traffic):
//   u    = bf16( z * dinv[:,None] )           [N,64] bf16
//   agg1 = u_d + sum u_s   (fp32 accum)       [N,64] fp32
//   x1   = relu(dinv*(agg1@W1)+b1)            [N,128] fp32
//   hs2  = bf16( dinv*(x1@W2) )               [N,64] bf16
//   out  = dinv*(hs2_d + sum hs2_s) + b2      [N,64] fp32

#define WAVE 64
#define BSHIFT 8
#define NPB 256              // nodes per bucket
#define CAP 5120             // max edges per bucket (mean 4096, +16 sigma)
#define CH 4096              // edges per WG in bin_edges
#define NBMAX 512

__device__ inline float bf16_to_f32(unsigned short h) {
    return __uint_as_float(((unsigned int)h) << 16);
}
__device__ inline unsigned short f32_to_bf16(float f) {
    unsigned int x = __float_as_uint(f);
    return (unsigned short)((x + 0x7FFFu + ((x >> 16) & 1u)) >> 16);   // RNE
}

// ---------------- utility ----------------
__global__ void zero_i32(int* __restrict__ p, int n) {
    int i = blockIdx.x * blockDim.x + threadIdx.x;
    if (i < n) p[i] = 0;
}

// ---------------- bin_edges: scatter edges into bucket-strided ebuf ---------
__global__ __launch_bounds__(256) void bin_edges(
        const int* __restrict__ src, const int* __restrict__ dst,
        int* __restrict__ bcursor, int2* __restrict__ ebuf, int E, int NB)
{
    __shared__ int hist[NBMAX];
    __shared__ int cur[NBMAX];
    const int t  = threadIdx.x;
    const int e0 = blockIdx.x * CH;

    for (int b = t; b < NB; b += 256) hist[b] = 0;
    __syncthreads();

#pragma unroll
    for (int j = 0; j < CH / 256; ++j) {
        int e = e0 + j * 256 + t;
        if (e < E) atomicAdd(&hist[dst[e] >> BSHIFT], 1);
    }
    __syncthreads();

    for (int b = t; b < NB; b += 256) {
        int c = hist[b];
        cur[b] = (c > 0) ? atomicAdd(&bcursor[b], c) : 0;
    }
    __syncthreads();

#pragma unroll
    for (int j = 0; j < CH / 256; ++j) {
        int e = e0 + j * 256 + t;
        if (e < E) {
            int s = src[e], d = dst[e];
            int b = d >> BSHIFT;
            int pos = atomicAdd(&cur[b], 1);
            ebuf[(size_t)b * CAP + pos] = make_int2(s, d);
        }
    }
}

// ---------------- build_csr: one WG per bucket ----------------
__global__ __launch_bounds__(256) void build_csr(
        const int2* __restrict__ ebuf, const int* __restrict__ bcursor,
        float* __restrict__ dinv, int* __restrict__ rbeg, int* __restrict__ rend,
        int* __restrict__ csr, int N)
{
    __shared__ int h[NPB];
    __shared__ int tmp[NPB];
    const int t   = threadIdx.x;
    const int b   = blockIdx.x;
    const int n0  = b << BSHIFT;
    const int cnt = bcursor[b];
    const size_t base = (size_t)b * CAP;

    h[t] = 0;
    __syncthreads();

    for (int i = t; i < cnt; i += 256)
        atomicAdd(&h[ebuf[base + i].y - n0], 1);
    __syncthreads();

    int deg = h[t];
    tmp[t] = deg;
    __syncthreads();
    for (int off = 1; off < 256; off <<= 1) {
        int x = (t >= off) ? tmp[t - off] : 0;
        __syncthreads();
        tmp[t] += x;
        __syncthreads();
    }
    int st = tmp[t] - deg;

    int node = n0 + t;
    if (node < N) {
        dinv[node] = rsqrtf((float)deg + 1.0f);
        rbeg[node] = (int)base + st;
        rend[node] = (int)base + st + deg;
    }
    h[t] = st;
    __syncthreads();

    for (int i = t; i < cnt; i += 256) {
        int2 e = ebuf[base + i];
        int p = atomicAdd(&h[e.y - n0], 1);
        csr[base + p] = e.x;
    }
}

// ---------------- scale: u = bf16(z * dinv[:,None]) ------------------------
__global__ void scale_to_bf16(const float* __restrict__ z, const float* __restrict__ dinv,
                              unsigned short* __restrict__ u, int N)
{
    int i = blockIdx.x * blockDim.x + threadIdx.x;   // over N*16 float4s
    if (i >= N * 16) return;
    float di = dinv[i >> 4];
    float4 v = ((const float4*)z)[i];
    ushort4 o;
    o.x = f32_to_bf16(v.x * di);
    o.y = f32_to_bf16(v.y * di);
    o.z = f32_to_bf16(v.z * di);
    o.w = f32_to_bf16(v.w * di);
    ((ushort4*)u)[i] = o;
}

// ---------------- GEMM, dinv-scaled epilogue (+bias/relu / bf16 out) --------
// out[r, :] = [relu]( dinv[r] * (A[r, :] @ W) [+ b] )
template<int K, int F, int ROWS, bool ADD_BIAS, bool RELU, bool BF16_OUT>
__global__ __launch_bounds__(256) void gemm_fused(
        const float* __restrict__ A, const float* __restrict__ W,
        const float* __restrict__ dinv, const float* __restrict__ b,
        void* __restrict__ out_, int N)
{
    constexpr int C4  = F / 4;        // float4 output columns
    constexpr int G   = 256 / C4;     // row groups
    constexpr int RPT = ROWS / G;     // rows per thread
    constexpr int KQ  = K / 4;        // float4 k-chunks
    constexpr int AST = KQ + 1;       // padded A row stride
    __shared__ float4 Wl[K * C4];
    __shared__ float4 Al[ROWS * AST];

    const int tid  = threadIdx.x;
    const int row0 = blockIdx.x * ROWS;

    for (int i = tid; i < K * C4; i += 256) Wl[i] = ((const float4*)W)[i];
    for (int i = tid; i < ROWS * KQ; i += 256) {
        int r = i / KQ, kq = i % KQ;
        int gr = row0 + r;
        float4 v = make_float4(0.f, 0.f, 0.f, 0.f);
        if (gr < N) v = ((const float4*)(A + (size_t)gr * K))[kq];
        Al[r * AST + kq] = v;
    }
    __syncthreads();

    const int c4 = tid % C4;
    const int rg = tid / C4;

    float4 acc[RPT];
#pragma unroll
    for (int r = 0; r < RPT; ++r) acc[r] = make_float4(0.f, 0.f, 0.f, 0.f);

#pragma unroll 2
    for (int kq = 0; kq < KQ; ++kq) {
        float4 w0 = Wl[(4 * kq + 0) * C4 + c4];
        float4 w1 = Wl[(4 * kq + 1) * C4 + c4];
        float4 w2 = Wl[(4 * kq + 2) * C4 + c4];
        float4 w3 = Wl[(4 * kq + 3) * C4 + c4];
#pragma unroll
        for (int r = 0; r < RPT; ++r) {
            float4 a = Al[(rg * RPT + r) * AST + kq];
            acc[r].x += a.x * w0.x; acc[r].y += a.x * w0.y;
            acc[r].z += a.x * w0.z; acc[r].w += a.x * w0.w;
            acc[r].x += a.y * w1.x; acc[r].y += a.y * w1.y;
            acc[r].z += a.y * w1.z; acc[r].w += a.y * w1.w;
            acc[r].x += a.z * w2.x; acc[r].y += a.z * w2.y;
            acc[r].z += a.z * w2.z; acc[r].w += a.z * w2.w;
            acc[r].x += a.w * w3.x; acc[r].y += a.w * w3.y;
            acc[r].z += a.w * w3.z; acc[r].w += a.w * w3.w;
        }
    }

#pragma unroll
    for (int r = 0; r < RPT; ++r) {
        int gr = row0 + rg * RPT + r;
        if (gr < N) {
            float di = dinv[gr];
            float4 o = acc[r];
            o.x *= di; o.y *= di; o.z *= di; o.w *= di;
            if (ADD_BIAS) {
                float4 bb = ((const float4*)b)[c4];
                o.x += bb.x; o.y += bb.y; o.z += bb.z; o.w += bb.w;
            }
            if (RELU) {
                o.x = fmaxf(o.x, 0.0f); o.y = fmaxf(o.y, 0.0f);
                o.z = fmaxf(o.z, 0.0f); o.w = fmaxf(o.w, 0.0f);
            }
            if (BF16_OUT) {
                ushort4 ob;
                ob.x = f32_to_bf16(o.x); ob.y = f32_to_bf16(o.y);
                ob.z = f32_to_bf16(o.z); ob.w = f32_to_bf16(o.w);
                ((ushort4*)((unsigned short*)out_ + (size_t)gr * F))[c4] = ob;
            } else {
                ((float4*)((float*)out_ + (size_t)gr * F))[c4] = o;
            }
        }
    }
}

// ---------------- aggregate (F=64, bf16 rows), one wave per node -----------
// PRE:  out_d = hs_d + sum hs_s                (POST=false)
// POST: out_d = dinv_d*(hs_d + sum hs_s) + b   (POST=true)
// hs rows are 64 bf16 = 128 B; lane l holds feature l as one ushort load.
template<bool POST>
__global__ __launch_bounds__(256) void aggregate64_bf16(
        const unsigned short* __restrict__ hs, const int* __restrict__ rbeg,
        const int* __restrict__ rend, const int* __restrict__ csr,
        const float* __restrict__ dinv, const float* __restrict__ b,
        float* __restrict__ out, int N)
{
    int node = (int)((blockIdx.x * (size_t)blockDim.x + threadIdx.x) >> 6);
    int lane = threadIdx.x & 63;
    if (node >= N) return;
    node = __builtin_amdgcn_readfirstlane(node);   // wave-uniform -> scalar loads

    const int beg = rbeg[node];
    const int end = rend[node];

    float acc = bf16_to_f32(hs[(size_t)node * 64 + lane]);   // self-loop term

    int e = beg;
    for (; e + 16 <= end; e += 16) {
        int s[16];
#pragma unroll
        for (int j = 0; j < 16; ++j) s[j] = csr[e + j];
        float v[16];
#pragma unroll
        for (int j = 0; j < 16; ++j) v[j] = bf16_to_f32(hs[(size_t)s[j] * 64 + lane]);
        float t0 = ((v[0] + v[1]) + (v[2] + v[3])) + ((v[4] + v[5]) + (v[6] + v[7]));
        float t1 = ((v[8] + v[9]) + (v[10] + v[11])) + ((v[12] + v[13]) + (v[14] + v[15]));
        acc += t0 + t1;
    }
    for (; e + 4 <= end; e += 4) {
        int s0 = csr[e+0], s1 = csr[e+1], s2 = csr[e+2], s3 = csr[e+3];
        float v0 = bf16_to_f32(hs[(size_t)s0 * 64 + lane]);
        float v1 = bf16_to_f32(hs[(size_t)s1 * 64 + lane]);
        float v2 = bf16_to_f32(hs[(size_t)s2 * 64 + lane]);
        float v3 = bf16_to_f32(hs[(size_t)s3 * 64 + lane]);
        acc += (v0 + v1) + (v2 + v3);
    }
    for (; e < end; ++e)
        acc += bf16_to_f32(hs[(size_t)csr[e] * 64 + lane]);

    float o = acc;
    if (POST) o = dinv[node] * acc + b[lane];
    out[(size_t)node * 64 + lane] = o;
}

static inline size_t align_up(size_t x, size_t a) { return (x + a - 1) / a * a; }

extern "C" void kernel_launch(void* const* d_in, const int* in_sizes, int n_in,
                              void* d_out, int out_size, void* d_ws, size_t ws_size,
                              hipStream_t stream) {
    const float* z    = (const float*)d_in[0];   // [N,64]
    const int*   eidx = (const int*)d_in[1];     // [2,E]: src row then dst row
    const float* W1   = (const float*)d_in[2];   // [64,128]
    const float* b1   = (const float*)d_in[3];   // [128]
    const float* W2   = (const float*)d_in[4];   // [128,64]
    const float* b2   = (const float*)d_in[5];   // [64]
    float* out = (float*)d_out;                  // [N,64]

    const int N = in_sizes[0] / 64;
    const int E = in_sizes[1] / 2;
    const int* src = eidx;
    const int* dst = eidx + E;
    const int NB = (N + NPB - 1) >> BSHIFT;      // 391 for N=100000

    // Workspace: small arrays | bufA (N*64*4 B) | bufB (N*64*4 B) | bufC (N*128*4 B)
    // u (bf16, 12.8 MB) and later hs2 (bf16) live in bufA; agg1 fp32 in bufB;
    // x1 fp32 in bufC (ebuf aliases bufC during CSR build).
    char* ws = (char*)d_ws;
    size_t off = 0;
    float* dinv    = (float*)(ws + off); off = align_up(off + (size_t)N * 4, 512);
    int*   rbeg    = (int*)  (ws + off); off = align_up(off + (size_t)N * 4, 512);
    int*   rend    = (int*)  (ws + off); off = align_up(off + (size_t)N * 4, 512);
    int*   bcursor = (int*)  (ws + off); off = align_up(off + (size_t)NBMAX * 4, 512);
    int*   csr     = (int*)  (ws + off); off = align_up(off + (size_t)NB * CAP * 4, 512);
    float* bufA    = (float*)(ws + off); off = align_up(off + (size_t)N * 64 * 4, 512);
    float* bufB    = (float*)(ws + off); off = align_up(off + (size_t)N * 64 * 4, 512);
    float* bufC    = (float*)(ws + off); off = align_up(off + (size_t)N * 128 * 4, 512);
    int2*  ebuf    = (int2*)bufC;
    (void)ws_size;

    unsigned short* u    = (unsigned short*)bufA;   // bf16 z*dinv
    float*          agg1 = bufB;                    // fp32 aggregated u
    float*          x1   = bufC;                    // fp32 layer-1 output
    unsigned short* hs2  = (unsigned short*)bufA;   // bf16 layer-2 pre-aggregate

    // ---- CSR build ----
    zero_i32<<<(NB + 255) / 256, 256, 0, stream>>>(bcursor, NB);
    bin_edges<<<(E + CH - 1) / CH, 256, 0, stream>>>(src, dst, bcursor, ebuf, E, NB);
    build_csr<<<NB, 256, 0, stream>>>(ebuf, bcursor, dinv, rbeg, rend, csr, N);

    // ---- layer 1 (aggregate pre-GEMM in 64-dim bf16 space) ----
    scale_to_bf16<<<((size_t)N * 16 + 255) / 256, 256, 0, stream>>>(z, dinv, u, N);
    aggregate64_bf16<false><<<(N + 3) / 4, 256, 0, stream>>>(u, rbeg, rend, csr, dinv, nullptr, agg1, N);
    constexpr int ROWS = 64;
    gemm_fused<64, 128, ROWS, true, true, false><<<(N + ROWS - 1) / ROWS, 256, 0, stream>>>(
        agg1, W1, dinv, b1, x1, N);

    // ---- layer 2 (aggregate post-GEMM in 64-dim bf16 space) ----
    gemm_fused<128, 64, ROWS, false, false, true><<<(N + ROWS - 1) / ROWS, 256, 0, stream>>>(
        x1, W2, dinv, nullptr, hs2, N);
    aggregate64_bf16<true><<<(N + 3) / 4, 256, 0, stream>>>(hs2, rbeg, rend, csr, dinv, b2, out, N);
}

// Round 8
// 276.360 us; speedup vs baseline: 4.7952x; 1.0163x over previous
//
#include <hip/hip_runtime.h>
#include <hip/hip_bf16.h>

// GCN 2-layer forward. Pipeline (6 kernels):
//   zero_i32      : clear bucket cursors
//   bin_edges     : edges -> bucket-strided (src,dst) pairs
//   build_csr     : per-bucket LDS histogram/prefix -> dinv, rbeg/rend, csr,
//                   AND u = bf16(z * dinv[:,None])   (scale fused here)
//   aggregate     : agg1_d = u_d + sum u_s           (fp32 accum, bf16 gather)
//   gemm12        : x1 = relu(dinv*(agg1@W1)+b1) in LDS only;
//                   hs2 = bf16(dinv*(x1@W2))         (W2 overwrites W1 in LDS)
//   aggregate     : out_d = dinv_d*(hs2_d + sum hs2_s) + b2

#define WAVE 64
#define BSHIFT 8
#define NPB 256              // nodes per bucket
#define CAP 5120             // max edges per bucket (mean 4096, +16 sigma)
#define CH 4096              // edges per WG in bin_edges
#define NBMAX 512

__device__ inline float bf16_to_f32(unsigned short h) {
    return __uint_as_float(((unsigned int)h) << 16);
}
__device__ inline unsigned short f32_to_bf16(float f) {
    unsigned int x = __float_as_uint(f);
    return (unsigned short)((x + 0x7FFFu + ((x >> 16) & 1u)) >> 16);   // RNE
}

// ---------------- utility ----------------
__global__ void zero_i32(int* __restrict__ p, int n) {
    int i = blockIdx.x * blockDim.x + threadIdx.x;
    if (i < n) p[i] = 0;
}

// ---------------- bin_edges: scatter edges into bucket-strided ebuf ---------
__global__ __launch_bounds__(256) void bin_edges(
        const int* __restrict__ src, const int* __restrict__ dst,
        int* __restrict__ bcursor, int2* __restrict__ ebuf, int E, int NB)
{
    __shared__ int hist[NBMAX];
    __shared__ int cur[NBMAX];
    const int t  = threadIdx.x;
    const int e0 = blockIdx.x * CH;

    for (int b = t; b < NB; b += 256) hist[b] = 0;
    __syncthreads();

#pragma unroll
    for (int j = 0; j < CH / 256; ++j) {
        int e = e0 + j * 256 + t;
        if (e < E) atomicAdd(&hist[dst[e] >> BSHIFT], 1);
    }
    __syncthreads();

    for (int b = t; b < NB; b += 256) {
        int c = hist[b];
        cur[b] = (c > 0) ? atomicAdd(&bcursor[b], c) : 0;
    }
    __syncthreads();

#pragma unroll
    for (int j = 0; j < CH / 256; ++j) {
        int e = e0 + j * 256 + t;
        if (e < E) {
            int s = src[e], d = dst[e];
            int b = d >> BSHIFT;
            int pos = atomicAdd(&cur[b], 1);
            ebuf[(size_t)b * CAP + pos] = make_int2(s, d);
        }
    }
}

// ---------------- build_csr + fused u = bf16(z*dinv) ----------------
__global__ __launch_bounds__(256) void build_csr(
        const int2* __restrict__ ebuf, const int* __restrict__ bcursor,
        const float* __restrict__ z, float* __restrict__ dinv,
        int* __restrict__ rbeg, int* __restrict__ rend,
        int* __restrict__ csr, unsigned short* __restrict__ u, int N)
{
    __shared__ int   h[NPB];
    __shared__ int   tmp[NPB];
    __shared__ float sdv[NPB];
    const int t   = threadIdx.x;
    const int b   = blockIdx.x;
    const int n0  = b << BSHIFT;
    const int cnt = bcursor[b];
    const size_t base = (size_t)b * CAP;

    h[t] = 0;
    __syncthreads();

    for (int i = t; i < cnt; i += 256)
        atomicAdd(&h[ebuf[base + i].y - n0], 1);
    __syncthreads();

    int deg = h[t];
    tmp[t] = deg;
    __syncthreads();
    for (int off = 1; off < 256; off <<= 1) {
        int x = (t >= off) ? tmp[t - off] : 0;
        __syncthreads();
        tmp[t] += x;
        __syncthreads();
    }
    int st = tmp[t] - deg;

    int node = n0 + t;
    float di = rsqrtf((float)deg + 1.0f);
    sdv[t] = di;
    if (node < N) {
        dinv[node] = di;
        rbeg[node] = (int)base + st;
        rend[node] = (int)base + st + deg;
    }
    h[t] = st;
    __syncthreads();   // covers both h-cursor reset and sdv visibility

    for (int i = t; i < cnt; i += 256) {
        int2 e = ebuf[base + i];
        int p = atomicAdd(&h[e.y - n0], 1);
        csr[base + p] = e.x;
    }

    // fused scale: u rows for this bucket (coalesced: 16 threads per row)
    const int nloc = (N - n0 < NPB) ? (N - n0) : NPB;
    for (int i = t; i < nloc * 16; i += 256) {
        int r = i >> 4, kq = i & 15;
        float d2 = sdv[r];
        float4 v = ((const float4*)(z + (size_t)(n0 + r) * 64))[kq];
        ushort4 o;
        o.x = f32_to_bf16(v.x * d2);
        o.y = f32_to_bf16(v.y * d2);
        o.z = f32_to_bf16(v.z * d2);
        o.w = f32_to_bf16(v.w * d2);
        ((ushort4*)(u + (size_t)(n0 + r) * 64))[kq] = o;
    }
}

// ---------------- aggregate (F=64, bf16 rows), one wave per node -----------
// PRE:  out_d = hs_d + sum hs_s                (POST=false, fp32 out)
// POST: out_d = dinv_d*(hs_d + sum hs_s) + b   (POST=true,  fp32 out)
template<bool POST>
__global__ __launch_bounds__(256) void aggregate64_bf16(
        const unsigned short* __restrict__ hs, const int* __restrict__ rbeg,
        const int* __restrict__ rend, const int* __restrict__ csr,
        const float* __restrict__ dinv, const float* __restrict__ b,
        float* __restrict__ out, int N)
{
    int node = (int)((blockIdx.x * (size_t)blockDim.x + threadIdx.x) >> 6);
    int lane = threadIdx.x & 63;
    if (node >= N) return;
    node = __builtin_amdgcn_readfirstlane(node);   // wave-uniform -> scalar loads

    const int beg = rbeg[node];
    const int end = rend[node];

    float acc = bf16_to_f32(hs[(size_t)node * 64 + lane]);   // self-loop term

    int e = beg;
    for (; e + 16 <= end; e += 16) {
        int s[16];
#pragma unroll
        for (int j = 0; j < 16; ++j) s[j] = csr[e + j];
        float v[16];
#pragma unroll
        for (int j = 0; j < 16; ++j) v[j] = bf16_to_f32(hs[(size_t)s[j] * 64 + lane]);
        float t0 = ((v[0] + v[1]) + (v[2] + v[3])) + ((v[4] + v[5]) + (v[6] + v[7]));
        float t1 = ((v[8] + v[9]) + (v[10] + v[11])) + ((v[12] + v[13]) + (v[14] + v[15]));
        acc += t0 + t1;
    }
    for (; e + 4 <= end; e += 4) {
        int s0 = csr[e+0], s1 = csr[e+1], s2 = csr[e+2], s3 = csr[e+3];
        float v0 = bf16_to_f32(hs[(size_t)s0 * 64 + lane]);
        float v1 = bf16_to_f32(hs[(size_t)s1 * 64 + lane]);
        float v2 = bf16_to_f32(hs[(size_t)s2 * 64 + lane]);
        float v3 = bf16_to_f32(hs[(size_t)s3 * 64 + lane]);
        acc += (v0 + v1) + (v2 + v3);
    }
    for (; e < end; ++e)
        acc += bf16_to_f32(hs[(size_t)csr[e] * 64 + lane]);

    float o = acc;
    if (POST) o = dinv[node] * acc + b[lane];
    out[(size_t)node * 64 + lane] = o;
}

// ---------------- fused double GEMM ----------------
// Per 32-row tile:
//   x1 = relu(dinv*(agg1@W1)+b1)   -> LDS only  (phase 1, W1 in Wl)
//   hs2 = bf16(dinv*(x1@W2))       -> global    (phase 2, W2 overwrites Wl)
// LDS: Wl 32 KB + Al 8.7 KB + X1 16.9 KB + sdv = ~58.5 KB -> 2 WGs/CU.
#define TILE 32
__global__ __launch_bounds__(256) void gemm12(
        const float* __restrict__ agg1, const float* __restrict__ W1,
        const float* __restrict__ b1, const float* __restrict__ W2,
        const float* __restrict__ dinv, unsigned short* __restrict__ hs2, int N)
{
    __shared__ float4 Wl[2048];            // 32 KB: W1 (64x32 f4) then W2 (128x16 f4)
    __shared__ float4 Al[TILE * 17];       // agg1 tile, 16 f4/row + pad
    __shared__ float4 X1[TILE * 33];       // x1 tile, 32 f4/row + pad
    __shared__ float  sdv[TILE];

    const int tid  = threadIdx.x;
    const int row0 = blockIdx.x * TILE;

    // ---- stage W1 + A-tile + dinv ----
#pragma unroll
    for (int i = tid; i < 2048; i += 256) Wl[i] = ((const float4*)W1)[i];
    for (int i = tid; i < TILE * 16; i += 256) {
        int r = i >> 4, kq = i & 15;
        int gr = row0 + r;
        float4 v = make_float4(0.f, 0.f, 0.f, 0.f);
        if (gr < N) v = ((const float4*)(agg1 + (size_t)gr * 64))[kq];
        Al[r * 17 + kq] = v;
    }
    if (tid < TILE) {
        int gr = row0 + tid;
        sdv[tid] = (gr < N) ? dinv[gr] : 0.0f;
    }
    __syncthreads();

    // ---- phase 1: x1 = relu(dinv*(agg1@W1)+b1) -> X1 (LDS) ----
    {
        constexpr int C4 = 32, G = 8, RPT = TILE / G;   // 4 rows/thread
        const int c4 = tid % C4;
        const int rg = tid / C4;
        float4 acc[RPT];
#pragma unroll
        for (int r = 0; r < RPT; ++r) acc[r] = make_float4(0.f, 0.f, 0.f, 0.f);

#pragma unroll 2
        for (int kq = 0; kq < 16; ++kq) {
            float4 w0 = Wl[(4 * kq + 0) * C4 + c4];
            float4 w1 = Wl[(4 * kq + 1) * C4 + c4];
            float4 w2 = Wl[(4 * kq + 2) * C4 + c4];
            float4 w3 = Wl[(4 * kq + 3) * C4 + c4];
#pragma unroll
            for (int r = 0; r < RPT; ++r) {
                float4 a = Al[(rg * RPT + r) * 17 + kq];
                acc[r].x += a.x * w0.x; acc[r].y += a.x * w0.y;
                acc[r].z += a.x * w0.z; acc[r].w += a.x * w0.w;
                acc[r].x += a.y * w1.x; acc[r].y += a.y * w1.y;
                acc[r].z += a.y * w1.z; acc[r].w += a.y * w1.w;
                acc[r].x += a.z * w2.x; acc[r].y += a.z * w2.y;
                acc[r].z += a.z * w2.z; acc[r].w += a.z * w2.w;
                acc[r].x += a.w * w3.x; acc[r].y += a.w * w3.y;
                acc[r].z += a.w * w3.z; acc[r].w += a.w * w3.w;
            }
        }

        float4 bb = ((const float4*)b1)[c4];
#pragma unroll
        for (int r = 0; r < RPT; ++r) {
            int lr = rg * RPT + r;
            float di = sdv[lr];
            float4 o = acc[r];
            o.x = fmaxf(o.x * di + bb.x, 0.0f);
            o.y = fmaxf(o.y * di + bb.y, 0.0f);
            o.z = fmaxf(o.z * di + bb.z, 0.0f);
            o.w = fmaxf(o.w * di + bb.w, 0.0f);
            X1[lr * 33 + c4] = o;
        }
    }
    __syncthreads();          // phase-1 Wl reads done, X1 written

    // ---- restage W2 over W1 ----
#pragma unroll
    for (int i = tid; i < 2048; i += 256) Wl[i] = ((const float4*)W2)[i];
    __syncthreads();

    // ---- phase 2: hs2 = bf16(dinv*(x1@W2)) ----
    {
        constexpr int C4 = 16, G = 16, RPT = TILE / G;   // 2 rows/thread
        const int c4 = tid % C4;
        const int rg = tid / C4;
        float4 acc[RPT];
#pragma unroll
        for (int r = 0; r < RPT; ++r) acc[r] = make_float4(0.f, 0.f, 0.f, 0.f);

#pragma unroll 2
        for (int kq = 0; kq < 32; ++kq) {
            float4 w0 = Wl[(4 * kq + 0) * C4 + c4];
            float4 w1 = Wl[(4 * kq + 1) * C4 + c4];
            float4 w2 = Wl[(4 * kq + 2) * C4 + c4];
            float4 w3 = Wl[(4 * kq + 3) * C4 + c4];
#pragma unroll
            for (int r = 0; r < RPT; ++r) {
                float4 a = X1[(rg * RPT + r) * 33 + kq];
                acc[r].x += a.x * w0.x; acc[r].y += a.x * w0.y;
                acc[r].z += a.x * w0.z; acc[r].w += a.x * w0.w;
                acc[r].x += a.y * w1.x; acc[r].y += a.y * w1.y;
                acc[r].z += a.y * w1.z; acc[r].w += a.y * w1.w;
                acc[r].x += a.z * w2.x; acc[r].y += a.z * w2.y;
                acc[r].z += a.z * w2.z; acc[r].w += a.z * w2.w;
                acc[r].x += a.w * w3.x; acc[r].y += a.w * w3.y;
                acc[r].z += a.w * w3.z; acc[r].w += a.w * w3.w;
            }
        }

#pragma unroll
        for (int r = 0; r < RPT; ++r) {
            int lr = rg * RPT + r;
            int gr = row0 + lr;
            if (gr < N) {
                float di = sdv[lr];
                float4 o = acc[r];
                ushort4 ob;
                ob.x = f32_to_bf16(o.x * di);
                ob.y = f32_to_bf16(o.y * di);
                ob.z = f32_to_bf16(o.z * di);
                ob.w = f32_to_bf16(o.w * di);
                ((ushort4*)(hs2 + (size_t)gr * 64))[c4] = ob;
            }
        }
    }
}

static inline size_t align_up(size_t x, size_t a) { return (x + a - 1) / a * a; }

extern "C" void kernel_launch(void* const* d_in, const int* in_sizes, int n_in,
                              void* d_out, int out_size, void* d_ws, size_t ws_size,
                              hipStream_t stream) {
    const float* z    = (const float*)d_in[0];   // [N,64]
    const int*   eidx = (const int*)d_in[1];     // [2,E]: src row then dst row
    const float* W1   = (const float*)d_in[2];   // [64,128]
    const float* b1   = (const float*)d_in[3];   // [128]
    const float* W2   = (const float*)d_in[4];   // [128,64]
    const float* b2   = (const float*)d_in[5];   // [64]
    float* out = (float*)d_out;                  // [N,64]

    const int N = in_sizes[0] / 64;
    const int E = in_sizes[1] / 2;
    const int* src = eidx;
    const int* dst = eidx + E;
    const int NB = (N + NPB - 1) >> BSHIFT;      // 391 for N=100000

    // Workspace: small arrays | bufA (N*64*4) | bufB (N*64*4) | bufC (N*128*4)
    // u (bf16) in bufA; agg1 fp32 in bufB; hs2 (bf16) overwrites u in bufA
    // (u is dead after aggregate #1); ebuf aliases bufC.
    char* ws = (char*)d_ws;
    size_t off = 0;
    float* dinv    = (float*)(ws + off); off = align_up(off + (size_t)N * 4, 512);
    int*   rbeg    = (int*)  (ws + off); off = align_up(off + (size_t)N * 4, 512);
    int*   rend    = (int*)  (ws + off); off = align_up(off + (size_t)N * 4, 512);
    int*   bcursor = (int*)  (ws + off); off = align_up(off + (size_t)NBMAX * 4, 512);
    int*   csr     = (int*)  (ws + off); off = align_up(off + (size_t)NB * CAP * 4, 512);
    float* bufA    = (float*)(ws + off); off = align_up(off + (size_t)N * 64 * 4, 512);
    float* bufB    = (float*)(ws + off); off = align_up(off + (size_t)N * 64 * 4, 512);
    float* bufC    = (float*)(ws + off); off = align_up(off + (size_t)N * 128 * 4, 512);
    int2*  ebuf    = (int2*)bufC;
    (void)ws_size;

    unsigned short* u    = (unsigned short*)bufA;   // bf16 z*dinv
    float*          agg1 = bufB;                    // fp32 aggregated u
    unsigned short* hs2  = (unsigned short*)bufA;   // bf16 layer-2 pre-aggregate

    // ---- CSR build (+ fused dinv & u-scale) ----
    zero_i32<<<(NB + 255) / 256, 256, 0, stream>>>(bcursor, NB);
    bin_edges<<<(E + CH - 1) / CH, 256, 0, stream>>>(src, dst, bcursor, ebuf, E, NB);
    build_csr<<<NB, 256, 0, stream>>>(ebuf, bcursor, z, dinv, rbeg, rend, csr, u, N);

    // ---- layer 1 aggregate (pre-GEMM, bf16 gather) ----
    aggregate64_bf16<false><<<(N + 3) / 4, 256, 0, stream>>>(u, rbeg, rend, csr, dinv, nullptr, agg1, N);

    // ---- fused GEMM1+GEMM2 (x1 never leaves LDS) ----
    gemm12<<<(N + TILE - 1) / TILE, 256, 0, stream>>>(agg1, W1, b1, W2, dinv, hs2, N);

    // ---- layer 2 aggregate (post-GEMM, bf16 gather) ----
    aggregate64_bf16<true><<<(N + 3) / 4, 256, 0, stream>>>(hs2, rbeg, rend, csr, dinv, b2, out, N);
}

// Round 9
// 237.307 us; speedup vs baseline: 5.5843x; 1.1646x over previous
//
#include <hip/hip_runtime.h>
#include <hip/hip_bf16.h>

// GCN 2-layer forward. Pipeline (6 kernels):
//   prep          : zero bucket cursors + W1,W2 -> bf16 transposed (Wt[n][k])
//   bin_edges     : edges -> bucket-strided (src,dst) pairs
//   build_csr     : per-bucket LDS histogram/prefix -> dinv, rbeg/rend, csr,
//                   AND u = bf16(z * dinv[:,None])
//   aggregate PRE : agg1_d = bf16(u_d + sum u_s)      (fp32 accum, bf16 out)
//   gemm12_mfma   : x1 = relu(dinv*(agg1@W1)+b1) in LDS (bf16);
//                   hs2 = bf16(dinv*(x1@W2))          (both GEMMs on MFMA)
//   aggregate POST: out_d = dinv_d*(hs2_d + sum hs2_s) + b2   (fp32 out)

#define WAVE 64
#define BSHIFT 8
#define NPB 256              // nodes per bucket
#define CAP 5120             // max edges per bucket (mean 4096, +16 sigma)
#define CH 4096              // edges per WG in bin_edges
#define NBMAX 512

typedef __attribute__((ext_vector_type(8))) short bf16x8;
typedef __attribute__((ext_vector_type(4))) float f32x4;

__device__ inline float bf16_to_f32(unsigned short h) {
    return __uint_as_float(((unsigned int)h) << 16);
}
__device__ inline unsigned short f32_to_bf16(float f) {
    unsigned int x = __float_as_uint(f);
    return (unsigned short)((x + 0x7FFFu + ((x >> 16) & 1u)) >> 16);   // RNE
}

// ---------------- prep: zero cursors + W -> bf16 transposed ----------------
__global__ void prep(const float* __restrict__ W1, const float* __restrict__ W2,
                     unsigned short* __restrict__ W1t, unsigned short* __restrict__ W2t,
                     int* __restrict__ bcursor, int NB)
{
    int i = blockIdx.x * blockDim.x + threadIdx.x;
    if (i < NB) bcursor[i] = 0;
    if (i < 128 * 64) {          // W1t[n][k] = W1[k][n]  (W1 is [64][128])
        int n = i >> 6, k = i & 63;
        W1t[i] = f32_to_bf16(W1[k * 128 + n]);
    }
    if (i < 64 * 128) {          // W2t[n][k] = W2[k][n]  (W2 is [128][64])
        int n = i >> 7, k = i & 127;
        W2t[i] = f32_to_bf16(W2[k * 64 + n]);
    }
}

// ---------------- bin_edges: scatter edges into bucket-strided ebuf ---------
__global__ __launch_bounds__(256) void bin_edges(
        const int* __restrict__ src, const int* __restrict__ dst,
        int* __restrict__ bcursor, int2* __restrict__ ebuf, int E, int NB)
{
    __shared__ int hist[NBMAX];
    __shared__ int cur[NBMAX];
    const int t  = threadIdx.x;
    const int e0 = blockIdx.x * CH;

    for (int b = t; b < NB; b += 256) hist[b] = 0;
    __syncthreads();

#pragma unroll
    for (int j = 0; j < CH / 256; ++j) {
        int e = e0 + j * 256 + t;
        if (e < E) atomicAdd(&hist[dst[e] >> BSHIFT], 1);
    }
    __syncthreads();

    for (int b = t; b < NB; b += 256) {
        int c = hist[b];
        cur[b] = (c > 0) ? atomicAdd(&bcursor[b], c) : 0;
    }
    __syncthreads();

#pragma unroll
    for (int j = 0; j < CH / 256; ++j) {
        int e = e0 + j * 256 + t;
        if (e < E) {
            int s = src[e], d = dst[e];
            int b = d >> BSHIFT;
            int pos = atomicAdd(&cur[b], 1);
            ebuf[(size_t)b * CAP + pos] = make_int2(s, d);
        }
    }
}

// ---------------- build_csr + fused u = bf16(z*dinv) ----------------
__global__ __launch_bounds__(256) void build_csr(
        const int2* __restrict__ ebuf, const int* __restrict__ bcursor,
        const float* __restrict__ z, float* __restrict__ dinv,
        int* __restrict__ rbeg, int* __restrict__ rend,
        int* __restrict__ csr, unsigned short* __restrict__ u, int N)
{
    __shared__ int   h[NPB];
    __shared__ int   tmp[NPB];
    __shared__ float sdv[NPB];
    const int t   = threadIdx.x;
    const int b   = blockIdx.x;
    const int n0  = b << BSHIFT;
    const int cnt = bcursor[b];
    const size_t base = (size_t)b * CAP;

    h[t] = 0;
    __syncthreads();

    for (int i = t; i < cnt; i += 256)
        atomicAdd(&h[ebuf[base + i].y - n0], 1);
    __syncthreads();

    int deg = h[t];
    tmp[t] = deg;
    __syncthreads();
    for (int off = 1; off < 256; off <<= 1) {
        int x = (t >= off) ? tmp[t - off] : 0;
        __syncthreads();
        tmp[t] += x;
        __syncthreads();
    }
    int st = tmp[t] - deg;

    int node = n0 + t;
    float di = rsqrtf((float)deg + 1.0f);
    sdv[t] = di;
    if (node < N) {
        dinv[node] = di;
        rbeg[node] = (int)base + st;
        rend[node] = (int)base + st + deg;
    }
    h[t] = st;
    __syncthreads();   // covers h-cursor reset and sdv visibility

    for (int i = t; i < cnt; i += 256) {
        int2 e = ebuf[base + i];
        int p = atomicAdd(&h[e.y - n0], 1);
        csr[base + p] = e.x;
    }

    // fused scale: u rows for this bucket (16 threads per row, float4 reads)
    const int nloc = (N - n0 < NPB) ? (N - n0) : NPB;
    for (int i = t; i < nloc * 16; i += 256) {
        int r = i >> 4, kq = i & 15;
        float d2 = sdv[r];
        float4 v = ((const float4*)(z + (size_t)(n0 + r) * 64))[kq];
        ushort4 o;
        o.x = f32_to_bf16(v.x * d2);
        o.y = f32_to_bf16(v.y * d2);
        o.z = f32_to_bf16(v.z * d2);
        o.w = f32_to_bf16(v.w * d2);
        ((ushort4*)(u + (size_t)(n0 + r) * 64))[kq] = o;
    }
}

// ---------------- aggregate (F=64, bf16 rows), one wave per node -----------
// PRE  (POST=false): out = bf16(hs_d + sum hs_s)        -> ushort*
// POST (POST=true):  out = dinv_d*(hs_d + sum hs_s) + b -> float*
template<bool POST>
__global__ __launch_bounds__(256) void aggregate64_bf16(
        const unsigned short* __restrict__ hs, const int* __restrict__ rbeg,
        const int* __restrict__ rend, const int* __restrict__ csr,
        const float* __restrict__ dinv, const float* __restrict__ b,
        void* __restrict__ out_, int N)
{
    int node = (int)((blockIdx.x * (size_t)blockDim.x + threadIdx.x) >> 6);
    int lane = threadIdx.x & 63;
    if (node >= N) return;
    node = __builtin_amdgcn_readfirstlane(node);   // wave-uniform -> scalar loads

    const int beg = rbeg[node];
    const int end = rend[node];

    float acc = bf16_to_f32(hs[(size_t)node * 64 + lane]);   // self-loop term

    int e = beg;
    for (; e + 16 <= end; e += 16) {
        int s[16];
#pragma unroll
        for (int j = 0; j < 16; ++j) s[j] = csr[e + j];
        float v[16];
#pragma unroll
        for (int j = 0; j < 16; ++j) v[j] = bf16_to_f32(hs[(size_t)s[j] * 64 + lane]);
        float t0 = ((v[0] + v[1]) + (v[2] + v[3])) + ((v[4] + v[5]) + (v[6] + v[7]));
        float t1 = ((v[8] + v[9]) + (v[10] + v[11])) + ((v[12] + v[13]) + (v[14] + v[15]));
        acc += t0 + t1;
    }
    for (; e + 4 <= end; e += 4) {
        int s0 = csr[e+0], s1 = csr[e+1], s2 = csr[e+2], s3 = csr[e+3];
        float v0 = bf16_to_f32(hs[(size_t)s0 * 64 + lane]);
        float v1 = bf16_to_f32(hs[(size_t)s1 * 64 + lane]);
        float v2 = bf16_to_f32(hs[(size_t)s2 * 64 + lane]);
        float v3 = bf16_to_f32(hs[(size_t)s3 * 64 + lane]);
        acc += (v0 + v1) + (v2 + v3);
    }
    for (; e < end; ++e)
        acc += bf16_to_f32(hs[(size_t)csr[e] * 64 + lane]);

    if (POST) {
        float o = dinv[node] * acc + b[lane];
        ((float*)out_)[(size_t)node * 64 + lane] = o;
    } else {
        ((unsigned short*)out_)[(size_t)node * 64 + lane] = f32_to_bf16(acc);
    }
}

// ---------------- fused dual GEMM on MFMA ----------------
// Per 32-row tile:
//   phase 1: x1 = relu(dinv*(agg1@W1)+b1)  -> LDS bf16 (A-operand layout)
//   phase 2: hs2 = bf16(dinv*(x1@W2))      -> global
// mfma_f32_16x16x32_bf16 layouts (HW-verified, learn_hip m89/m91/m120):
//   A: lane holds A[m=lane&15][k = (lane>>4)*8 + j]  (8 contiguous bf16)
//   B: lane holds B[k=(lane>>4)*8+j][n=lane&15]  -> stage W transposed Wt[n][k]
//   C/D: col = lane&15, row = (lane>>4)*4 + reg
// LDS ~49.3 KB -> 3 WGs/CU. Padded strides (72/136 ushorts) keep reads ~2-way.
#define TILE 32
#define W1T_ST 72
#define W2T_ST 136
#define A_ST   72
#define X1_ST  136

__global__ __launch_bounds__(256) void gemm12_mfma(
        const unsigned short* __restrict__ agg1,   // bf16 [N][64]
        const unsigned short* __restrict__ W1t,    // bf16 [128][64]  (n-major)
        const float* __restrict__ b1,              // [128]
        const unsigned short* __restrict__ W2t,    // bf16 [64][128]  (n-major)
        const float* __restrict__ dinv,
        unsigned short* __restrict__ hs2, int N)
{
    __shared__ unsigned short sW1[128 * W1T_ST];
    __shared__ unsigned short sW2[64 * W2T_ST];
    __shared__ unsigned short sA[TILE * A_ST];
    __shared__ unsigned short sX[TILE * X1_ST];
    __shared__ float sdv[TILE];

    const int tid  = threadIdx.x;
    const int row0 = blockIdx.x * TILE;
    const int lane = tid & 63;
    const int wv   = tid >> 6;        // wave 0..3
    const int l16  = lane & 15;
    const int quad = lane >> 4;       // 0..3

    // ---- stage W1t (128 rows x 8 chunks of 8 bf16) ----
    for (int i = tid; i < 128 * 8; i += 256) {
        int r = i >> 3, c = i & 7;
        *(uint4*)&sW1[r * W1T_ST + c * 8] = *(const uint4*)&W1t[r * 64 + c * 8];
    }
    // ---- stage W2t (64 rows x 16 chunks) ----
    for (int i = tid; i < 64 * 16; i += 256) {
        int r = i >> 4, c = i & 15;
        *(uint4*)&sW2[r * W2T_ST + c * 8] = *(const uint4*)&W2t[r * 128 + c * 8];
    }
    // ---- stage A tile (32 rows x 8 chunks) ----
    for (int i = tid; i < TILE * 8; i += 256) {
        int r = i >> 3, c = i & 7;
        int gr = row0 + r;
        uint4 v = make_uint4(0u, 0u, 0u, 0u);
        if (gr < N) v = *(const uint4*)&agg1[(size_t)gr * 64 + c * 8];
        *(uint4*)&sA[r * A_ST + c * 8] = v;
    }
    if (tid < TILE) {
        int gr = row0 + tid;
        sdv[tid] = (gr < N) ? dinv[gr] : 0.0f;
    }
    __syncthreads();

    // ---- phase 1: 32x128 output, 16 MFMA tiles, 4 per wave ----
    {
        const int mt  = wv & 1;
        const int ntb = (wv >> 1) * 4;
        f32x4 acc[4];
#pragma unroll
        for (int t = 0; t < 4; ++t) acc[t] = (f32x4)0.0f;

#pragma unroll
        for (int k0 = 0; k0 < 64; k0 += 32) {
            bf16x8 af = *(const bf16x8*)&sA[(mt * 16 + l16) * A_ST + k0 + quad * 8];
#pragma unroll
            for (int t = 0; t < 4; ++t) {
                bf16x8 bf = *(const bf16x8*)&sW1[((ntb + t) * 16 + l16) * W1T_ST + k0 + quad * 8];
                acc[t] = __builtin_amdgcn_mfma_f32_16x16x32_bf16(af, bf, acc[t], 0, 0, 0);
            }
        }

#pragma unroll
        for (int t = 0; t < 4; ++t) {
            int col = (ntb + t) * 16 + l16;
            float bb = b1[col];
#pragma unroll
            for (int r = 0; r < 4; ++r) {
                int lr = mt * 16 + quad * 4 + r;
                float o = fmaxf(acc[t][r] * sdv[lr] + bb, 0.0f);
                sX[lr * X1_ST + col] = f32_to_bf16(o);
            }
        }
    }
    __syncthreads();

    // ---- phase 2: 32x64 output, 8 MFMA tiles, 2 per wave ----
    {
        const int mt  = wv & 1;
        const int ntb = (wv >> 1) * 2;
        f32x4 acc[2];
#pragma unroll
        for (int t = 0; t < 2; ++t) acc[t] = (f32x4)0.0f;

#pragma unroll
        for (int k0 = 0; k0 < 128; k0 += 32) {
            bf16x8 af = *(const bf16x8*)&sX[(mt * 16 + l16) * X1_ST + k0 + quad * 8];
#pragma unroll
            for (int t = 0; t < 2; ++t) {
                bf16x8 bf = *(const bf16x8*)&sW2[((ntb + t) * 16 + l16) * W2T_ST + k0 + quad * 8];
                acc[t] = __builtin_amdgcn_mfma_f32_16x16x32_bf16(af, bf, acc[t], 0, 0, 0);
            }
        }

#pragma unroll
        for (int t = 0; t < 2; ++t) {
            int col = (ntb + t) * 16 + l16;
#pragma unroll
            for (int r = 0; r < 4; ++r) {
                int lr = mt * 16 + quad * 4 + r;
                int gr = row0 + lr;
                if (gr < N)
                    hs2[(size_t)gr * 64 + col] = f32_to_bf16(acc[t][r] * sdv[lr]);
            }
        }
    }
}

static inline size_t align_up(size_t x, size_t a) { return (x + a - 1) / a * a; }

extern "C" void kernel_launch(void* const* d_in, const int* in_sizes, int n_in,
                              void* d_out, int out_size, void* d_ws, size_t ws_size,
                              hipStream_t stream) {
    const float* z    = (const float*)d_in[0];   // [N,64]
    const int*   eidx = (const int*)d_in[1];     // [2,E]: src row then dst row
    const float* W1   = (const float*)d_in[2];   // [64,128]
    const float* b1   = (const float*)d_in[3];   // [128]
    const float* W2   = (const float*)d_in[4];   // [128,64]
    const float* b2   = (const float*)d_in[5];   // [64]
    float* out = (float*)d_out;                  // [N,64]

    const int N = in_sizes[0] / 64;
    const int E = in_sizes[1] / 2;
    const int* src = eidx;
    const int* dst = eidx + E;
    const int NB = (N + NPB - 1) >> BSHIFT;      // 391 for N=100000

    // Workspace: small arrays | W1t | W2t | bufA | bufB | bufC
    // u (bf16) in bufA; agg1 (bf16) in bufB; hs2 (bf16) overwrites u in bufA;
    // ebuf aliases bufC (dead after build_csr).
    char* ws = (char*)d_ws;
    size_t off = 0;
    float* dinv    = (float*)(ws + off); off = align_up(off + (size_t)N * 4, 512);
    int*   rbeg    = (int*)  (ws + off); off = align_up(off + (size_t)N * 4, 512);
    int*   rend    = (int*)  (ws + off); off = align_up(off + (size_t)N * 4, 512);
    int*   bcursor = (int*)  (ws + off); off = align_up(off + (size_t)NBMAX * 4, 512);
    unsigned short* W1t = (unsigned short*)(ws + off); off = align_up(off + 8192 * 2, 512);
    unsigned short* W2t = (unsigned short*)(ws + off); off = align_up(off + 8192 * 2, 512);
    int*   csr     = (int*)  (ws + off); off = align_up(off + (size_t)NB * CAP * 4, 512);
    float* bufA    = (float*)(ws + off); off = align_up(off + (size_t)N * 64 * 4, 512);
    float* bufB    = (float*)(ws + off); off = align_up(off + (size_t)N * 64 * 4, 512);
    float* bufC    = (float*)(ws + off); off = align_up(off + (size_t)N * 128 * 4, 512);
    int2*  ebuf    = (int2*)bufC;
    (void)ws_size;

    unsigned short* u    = (unsigned short*)bufA;   // bf16 z*dinv
    unsigned short* agg1 = (unsigned short*)bufB;   // bf16 aggregated u
    unsigned short* hs2  = (unsigned short*)bufA;   // bf16 layer-2 pre-aggregate

    // ---- prep (cursor zero + W transpose/convert) ----
    prep<<<32, 256, 0, stream>>>(W1, W2, W1t, W2t, bcursor, NB);

    // ---- CSR build (+ fused dinv & u-scale) ----
    bin_edges<<<(E + CH - 1) / CH, 256, 0, stream>>>(src, dst, bcursor, ebuf, E, NB);
    build_csr<<<NB, 256, 0, stream>>>(ebuf, bcursor, z, dinv, rbeg, rend, csr, u, N);

    // ---- layer 1 aggregate (pre-GEMM, bf16 gather, bf16 out) ----
    aggregate64_bf16<false><<<(N + 3) / 4, 256, 0, stream>>>(u, rbeg, rend, csr, dinv, nullptr, agg1, N);

    // ---- fused dual GEMM on MFMA (x1 never leaves LDS) ----
    gemm12_mfma<<<(N + TILE - 1) / TILE, 256, 0, stream>>>(agg1, W1t, b1, W2t, dinv, hs2, N);

    // ---- layer 2 aggregate (post-GEMM, bf16 gather, fp32 out) ----
    aggregate64_bf16<true><<<(N + 3) / 4, 256, 0, stream>>>(hs2, rbeg, rend, csr, dinv, b2, out, N);
}